// Round 8
// baseline (815.068 us; speedup 1.0000x reference)
//
#include <hip/hip_runtime.h>

#define BB 8
#define NN 8192
#define SS 2048
#define DD1 64
#define DD2 128
#define CIN 192
#define CH1 256
#define CH2 128
#define RTOT (BB*NN)   // 65536
#define KCHUNK 256
#define NCHK 8
#define NBLK 512       // fused-MLP grid; co-residency guaranteed (see launch_bounds note)

typedef __attribute__((ext_vector_type(8))) short short8;
typedef __attribute__((ext_vector_type(4))) short shortx4;
typedef __attribute__((ext_vector_type(4))) float floatx4;
typedef __attribute__((ext_vector_type(4))) unsigned uintx4;

__device__ __forceinline__ unsigned short f2bf(float f) {
  unsigned u = __float_as_uint(f);
  u += 0x7fff + ((u >> 16) & 1);   // round-to-nearest-even
  return (unsigned short)(u >> 16);
}
__device__ __forceinline__ float bf2f(unsigned short h) {
  return __uint_as_float(((unsigned)h) << 16);
}

// ---------- fused prep: p2t transpose (2048 blks) + w0T (48) + w1T (32) + stats/ctr zero (1) ----------
__global__ __launch_bounds__(256) void prep(const float* __restrict__ points2, float* __restrict__ p2t,
                                            const float* __restrict__ w0, unsigned short* __restrict__ w0T,
                                            const float* __restrict__ w1, unsigned short* __restrict__ w1T,
                                            float* __restrict__ stats) {
  __shared__ float tile[32][33];
  int blk = blockIdx.x, tid = threadIdx.x;
  int tx = tid & 31, ty = tid >> 5;
  if (blk < 2048) {          // points2 [B][128][S] -> p2t [B][S][128]
    int z = blk >> 8, rem = blk & 255;
    int gy = rem >> 6, gx = rem & 63;
    const float* src = points2 + (size_t)z * DD2 * SS;
    float* dst = p2t + (size_t)z * DD2 * SS;
    int c0 = gx * 32, r0 = gy * 32;
    for (int i = ty; i < 32; i += 8)
      tile[i][tx] = src[(size_t)(r0 + i) * SS + (c0 + tx)];
    __syncthreads();
    for (int i = ty; i < 32; i += 8)
      dst[(size_t)(c0 + i) * DD2 + (r0 + tx)] = tile[tx][i];
  } else if (blk < 2096) {   // w0 [192][256] -> w0T [256][192] bf16
    int r = blk - 2048;
    int gy = r >> 3, gx = r & 7;
    int c0 = gx * 32, r0 = gy * 32;
    for (int i = ty; i < 32; i += 8)
      tile[i][tx] = w0[(size_t)(r0 + i) * CH1 + (c0 + tx)];
    __syncthreads();
    for (int i = ty; i < 32; i += 8)
      w0T[(size_t)(c0 + i) * CIN + (r0 + tx)] = f2bf(tile[tx][i]);
  } else if (blk < 2128) {   // w1 [256][128] -> w1T [128][256] bf16
    int r = blk - 2096;
    int gy = r >> 2, gx = r & 3;
    int c0 = gx * 32, r0 = gy * 32;
    for (int i = ty; i < 32; i += 8)
      tile[i][tx] = w1[(size_t)(r0 + i) * CH2 + (c0 + tx)];
    __syncthreads();
    for (int i = ty; i < 32; i += 8)
      w1T[(size_t)(c0 + i) * CH1 + (r0 + tx)] = f2bf(tile[tx][i]);
  } else {
    // stats[0..767] + 2 barrier counters (re-zeroed every graph replay)
    for (int i = tid; i < 772; i += 256) stats[i] = 0.f;
  }
}

// ---------- fused 3-NN + H0 build (512 threads = 8 waves/block) — unchanged from r5 ----------
__global__ __launch_bounds__(512) void knn3_gather(const float* __restrict__ xyz1,
                                                   const float* __restrict__ xyz2,
                                                   const float* __restrict__ points1,
                                                   const float* __restrict__ p2t,
                                                   unsigned short* __restrict__ H0) {
  __shared__ __align__(16) union LU {
    float coords[4][SS];     // 32 KB: x,y,z,|x|^2 — phases A-C
    float p1t[64][65];       // 16.6 KB, phases D-E (coords dead)
  } u;
  __shared__ __align__(16) unsigned ck[NCHK][64][4];   // 8 KB; tail reused post-rescore
  int* ldsI   = (int*)&ck[0][0][0];          // [64][3] — aliases ck, written after barrier
  float* ldsW = (float*)&ck[0][0][0] + 192;  // [64][3]
  int tid = threadIdx.x;
  int r0 = blockIdx.x * 64;
  int b = r0 >> 13;                 // N = 8192
  int n0 = r0 & (NN - 1);
  const float* x2 = xyz2 + (size_t)b * 3 * SS;
  for (int i = tid; i < SS; i += 512) {
    float xv = x2[i], yv = x2[SS + i], zv = x2[2 * SS + i];
    u.coords[0][i] = xv;
    u.coords[1][i] = yv;
    u.coords[2][i] = zv;
    u.coords[3][i] = xv * xv + yv * yv + zv * zv;
  }
  __syncthreads();
  int row = tid & 63, chk = tid >> 6;   // chunk wave-uniform -> LDS broadcasts
  int n = n0 + row;
  const float* x1 = xyz1 + (size_t)b * 3 * NN;
  float px = x1[n], py = x1[NN + n], pz = x1[2 * NN + n];
  float qx = -2.f * px, qy = -2.f * py, qz = -2.f * pz;
  float pp = px * px + py * py + pz * pz;
  floatx4 qx4 = {qx, qx, qx, qx}, qy4 = {qy, qy, qy, qy};
  floatx4 qz4 = {qz, qz, qz, qz}, pp4 = {pp, pp, pp, pp};
  unsigned c0 = 0xFFFFFFFFu, c1 = 0xFFFFFFFFu, c2 = 0xFFFFFFFFu, c3 = 0xFFFFFFFFu;
  int sbeg = (int)__builtin_amdgcn_readfirstlane((unsigned)(chk * KCHUNK));
#pragma unroll 2
  for (int s8 = sbeg; s8 < sbeg + KCHUNK; s8 += 8) {
#pragma unroll
    for (int p = 0; p < 2; ++p) {
      floatx4 xv = *(const floatx4*)&u.coords[0][s8 + 4 * p];
      floatx4 yv = *(const floatx4*)&u.coords[1][s8 + 4 * p];
      floatx4 zv = *(const floatx4*)&u.coords[2][s8 + 4 * p];
      floatx4 wv = *(const floatx4*)&u.coords[3][s8 + 4 * p];
      floatx4 d = xv * qx4 + wv;        // fma
      d = yv * qy4 + d;                 // fma
      d = zv * qz4 + d;                 // fma
      d = d + pp4;                      // add; d >= 0 (exact-ish |p-x|^2)
#pragma unroll
      for (int e = 0; e < 4; ++e) {
        unsigned k = (__float_as_uint(d[e]) & 0xFFFFF800u) | (unsigned)(s8 + 4 * p + e);
        // sorted top-4 insert via order statistics: new ci = med3(c[i-1], ci, k)
        unsigned m1, m2, m3;
        asm("v_med3_u32 %0, %1, %2, %3" : "=v"(m1) : "v"(c0), "v"(c1), "v"(k));
        asm("v_med3_u32 %0, %1, %2, %3" : "=v"(m2) : "v"(c1), "v"(c2), "v"(k));
        asm("v_med3_u32 %0, %1, %2, %3" : "=v"(m3) : "v"(c2), "v"(c3), "v"(k));
        c0 = __builtin_elementwise_min(c0, k);   // v_min_u32
        c1 = m1; c2 = m2; c3 = m3;
      }
    }
  }
  *(uintx4*)&ck[chk][row][0] = (uintx4){c0, c1, c2, c3};
  // prefetch the p1 tile into registers: latency hides under the rescore
  floatx4 pv[2];
  const float* p1 = points1 + (size_t)b * DD1 * NN;
#pragma unroll
  for (int t = 0; t < 2; ++t) {
    int i = tid + t * 512;             // 0..1023 = 64ch x 16 float4
    int ch = i >> 4, q = i & 15;
    pv[t] = *(const floatx4*)(p1 + (size_t)ch * NN + n0 + q * 4);
  }
  __syncthreads();
  // rescore into registers (reads u.coords + ck; no LDS writes yet)
  int j0, j1, j2; float fw0, fw1, fw2;
  if (tid < 64) {
    float qpx = x1[n0 + tid], qpy = x1[NN + n0 + tid], qpz = x1[2 * NN + n0 + tid];
    double e0 = 1e300, e1 = 1e300, e2 = 1e300;
    j0 = 0x7fffffff; j1 = 0x7fffffff; j2 = 0x7fffffff;
#pragma unroll
    for (int c = 0; c < NCHK; ++c)
#pragma unroll
      for (int t = 0; t < 4; ++t) {
        int si = (int)(ck[c][tid][t] & 0x7FFu);
        double dx = (double)u.coords[0][si] - (double)qpx;
        double dy = (double)u.coords[1][si] - (double)qpy;
        double dz = (double)u.coords[2][si] - (double)qpz;
        double d = dx * dx + dy * dy + dz * dz;
        if (d < e2 || (d == e2 && si < j2)) {
          if (d < e1 || (d == e1 && si < j1)) {
            e2 = e1; j2 = j1;
            if (d < e0 || (d == e0 && si < j0)) { e1 = e0; j1 = j0; e0 = d; j0 = si; }
            else                                { e1 = d;  j1 = si; }
          } else { e2 = d; j2 = si; }
        }
      }
    double rr0 = 1.0 / (e0 + 1e-8), rr1 = 1.0 / (e1 + 1e-8), rr2 = 1.0 / (e2 + 1e-8);
    double sw = rr0 + rr1 + rr2;
    fw0 = (float)(rr0 / sw); fw1 = (float)(rr1 / sw); fw2 = (float)(rr2 / sw);
  }
  __syncthreads();                      // all ck/coords reads done; aliased regions now writable
#pragma unroll
  for (int t = 0; t < 2; ++t) {         // p1t stores (coords region dead)
    int i = tid + t * 512;
    int ch = i >> 4, q = i & 15;
    u.p1t[ch][q * 4 + 0] = pv[t][0];    // component stores: [64][65] stays 2-way max
    u.p1t[ch][q * 4 + 1] = pv[t][1];
    u.p1t[ch][q * 4 + 2] = pv[t][2];
    u.p1t[ch][q * 4 + 3] = pv[t][3];
  }
  if (tid < 64) {                       // ldsI/ldsW into ck's (consumed) region
    ldsI[tid * 3 + 0] = j0; ldsI[tid * 3 + 1] = j1; ldsI[tid * 3 + 2] = j2;
    ldsW[tid * 3 + 0] = fw0; ldsW[tid * 3 + 1] = fw1; ldsW[tid * 3 + 2] = fw2;
  }
  __syncthreads();
  const float* base = p2t + (size_t)b * SS * DD2;
  unsigned short* Hrow = H0 + (size_t)r0 * CIN;
  for (int i = tid; i < 64 * 48; i += 512) {   // quad-columns: 48 per row
    int rr = i / 48;
    int qc = i - rr * 48;
    floatx4 v;
    if (qc < 16) {
      v[0] = u.p1t[qc * 4 + 0][rr];
      v[1] = u.p1t[qc * 4 + 1][rr];
      v[2] = u.p1t[qc * 4 + 2][rr];
      v[3] = u.p1t[qc * 4 + 3][rr];
    } else {
      int cc = qc * 4 - DD1;
      floatx4 g0 = *(const floatx4*)(base + (size_t)ldsI[rr * 3 + 0] * DD2 + cc);
      floatx4 g1 = *(const floatx4*)(base + (size_t)ldsI[rr * 3 + 1] * DD2 + cc);
      floatx4 g2 = *(const floatx4*)(base + (size_t)ldsI[rr * 3 + 2] * DD2 + cc);
      float w0 = ldsW[rr * 3 + 0], w1 = ldsW[rr * 3 + 1], w2 = ldsW[rr * 3 + 2];
#pragma unroll
      for (int e = 0; e < 4; ++e)
        v[e] = w0 * g0[e] + w1 * g1[e] + w2 * g2[e];
    }
    shortx4 pk;
#pragma unroll
    for (int e = 0; e < 4; ++e) pk[e] = (short)f2bf(v[e]);
    *(shortx4*)(Hrow + (size_t)rr * CIN + qc * 4) = pk;   // 8B coalesced stores
  }
}

// ---------- fused MLP: gemm0 -> gbar -> gemm1 (acc in regs) -> gbar -> BN1+ReLU out ----------
// PLAIN launch + software global barrier (cooperative API is incompatible with the
// harness's stream capture — r6 launch was silently dropped, output stayed zero).
// Deadlock-safety by construction: __launch_bounds__(256,2) caps VGPR<=256 -> >=2
// blocks/CU by VGPR; LDS 18KB -> 8/CU; threads -> 8/CU. 512 blocks <= 256CU*2 => all
// co-resident before any spin. Cross-block data = stats[] only, read via atomicAdd(p,0)
// (device-coherent path). Z0 rows are written AND read by the SAME block (L2-local,
// no coherence needed). Numerics bit-identical to the r5/r7 3-kernel chain.
__global__ __launch_bounds__(256, 2) void mlp_fused(
    const unsigned short* __restrict__ H0,
    const unsigned short* __restrict__ w0T, const float* __restrict__ cb0,
    const unsigned short* __restrict__ w1T, const float* __restrict__ cb1,
    const float* __restrict__ s0, const float* __restrict__ bb0,
    const float* __restrict__ s1, const float* __restrict__ bb1,
    float* __restrict__ stats, unsigned short* __restrict__ Z0,
    float* __restrict__ out)
{
  __shared__ __align__(16) unsigned short As[128 * 32];
  __shared__ __align__(16) unsigned short Bs[128 * 32];
  __shared__ float sa[256];
  __shared__ float sc[256];
  float* sum0 = stats;       float* sq0 = stats + 256;
  float* sum1 = stats + 512; float* sq1 = stats + 640;
  unsigned* bar = (unsigned*)(stats + 768);    // [2] counters, prep-zeroed each replay
  int tid = threadIdx.x;
  int lane = tid & 63, w = tid >> 6;
  int wm = (w & 1) << 6, wn = (w >> 1) << 6;
  int lm = lane & 15, lq = lane >> 4;
  int bm = blockIdx.x << 7;
  const float invR = 1.0f / RTOT;

  // ===== Phase A: Z0 = H0 @ w0T + cb0, two bn-halves sequentially =====
  for (int half = 0; half < 2; ++half) {
    int bn = half << 7;
    __syncthreads();                 // As free (prev half's colsum reads done)
    floatx4 acc[4][4] = {};
    for (int k0 = 0; k0 < CIN; k0 += 32) {
#pragma unroll
      for (int t = 0; t < 2; ++t) {  // A staging (H0) via global_load_lds
        int s = (w * 2 + t) * 64 + lane;
        int r = s >> 2;
        int kc = (s & 3) ^ ((r >> 2) & 3);
        const unsigned short* gp = H0 + (size_t)(bm + r) * CIN + (k0 + kc * 8);
        __builtin_amdgcn_global_load_lds(
            (const __attribute__((address_space(1))) void*)gp,
            (__attribute__((address_space(3))) void*)(As + (w * 2 + t) * 512),
            16, 0, 0);
      }
#pragma unroll
      for (int t = 0; t < 2; ++t) {  // B staging (w0T)
        int s = (w * 2 + t) * 64 + lane;
        int r = s >> 2;
        int kc = (s & 3) ^ ((r >> 2) & 3);
        const unsigned short* gp = w0T + (size_t)(bn + r) * CIN + (k0 + kc * 8);
        __builtin_amdgcn_global_load_lds(
            (const __attribute__((address_space(1))) void*)gp,
            (__attribute__((address_space(3))) void*)(Bs + (w * 2 + t) * 512),
            16, 0, 0);
      }
      __syncthreads();
      {
        short8 af[4], bfr[4];
        int kcl = lane >> 4;
#pragma unroll
        for (int mt = 0; mt < 4; ++mt) {
          int r = wm + mt * 16 + lm;
          int kp = kcl ^ ((r >> 2) & 3);
          af[mt] = *(const short8*)(As + r * 32 + kp * 8);
        }
#pragma unroll
        for (int nt = 0; nt < 4; ++nt) {
          int r = wn + nt * 16 + lm;
          int kp = kcl ^ ((r >> 2) & 3);
          bfr[nt] = *(const short8*)(Bs + r * 32 + kp * 8);
        }
#pragma unroll
        for (int mt = 0; mt < 4; ++mt)
#pragma unroll
          for (int nt = 0; nt < 4; ++nt)
            acc[mt][nt] = __builtin_amdgcn_mfma_f32_16x16x32_bf16(af[mt], bfr[nt], acc[mt][nt], 0, 0, 0);
      }
      __syncthreads();
    }
    // epilogue: Z0 store + column stats
    float bv[4];
#pragma unroll
    for (int nt = 0; nt < 4; ++nt) bv[nt] = cb0[bn + wn + nt * 16 + lm];
    float ps[4] = {}, pq[4] = {};
#pragma unroll
    for (int mt = 0; mt < 4; ++mt)
#pragma unroll
      for (int r4 = 0; r4 < 4; ++r4) {
        int rowg = bm + wm + mt * 16 + lq * 4 + r4;
        unsigned short* cp = Z0 + (size_t)rowg * CH1 + bn + wn + lm;
#pragma unroll
        for (int nt = 0; nt < 4; ++nt) {
          unsigned short us = f2bf(acc[mt][nt][r4] + bv[nt]);
          cp[nt * 16] = us;
          float vr = bf2f(us);           // stats on the bf16-rounded stored value
          ps[nt] += vr; pq[nt] += vr * vr;
        }
      }
    float* colsum = (float*)As;          // reuse LDS (all waves past last barrier)
    float* colsq  = colsum + 128;
    if (tid < 128) { colsum[tid] = 0.f; colsq[tid] = 0.f; }
    __syncthreads();
#pragma unroll
    for (int nt = 0; nt < 4; ++nt) {
      float s = ps[nt], q = pq[nt];
      s += __shfl_down(s, 32); s += __shfl_down(s, 16);
      q += __shfl_down(q, 32); q += __shfl_down(q, 16);
      if (lq == 0) {
        atomicAdd(&colsum[wn + nt * 16 + lm], s);
        atomicAdd(&colsq [wn + nt * 16 + lm], q);
      }
    }
    __syncthreads();
    if (tid < 128) {
      atomicAdd(&sum0[bn + tid], colsum[tid]);
      atomicAdd(&sq0 [bn + tid], colsq[tid]);
    }
  }
  // ---- global barrier 0 ----
  __syncthreads();
  if (tid == 0) {
    __threadfence();
    atomicAdd(&bar[0], 1u);
    while (atomicAdd(&bar[0], 0u) < NBLK) __builtin_amdgcn_s_sleep(8);
  }
  __syncthreads();

  // ===== Phase B: acc2 = relu(BN0(Z0)) @ w1T + cb1 (bn = 0, K = 256) =====
  for (int i = tid; i < CH1; i += 256) {
    float mu = atomicAdd(&sum0[i], 0.f) * invR;          // coherent read
    float var = atomicAdd(&sq0[i], 0.f) * invR - mu * mu;
    float aa = s0[i] * (1.0f / sqrtf(var + 1e-5f));
    sa[i] = aa; sc[i] = bb0[i] - mu * aa;
  }
  __syncthreads();
  floatx4 acc2[4][4] = {};
  float bv1[4];
#pragma unroll
  for (int nt = 0; nt < 4; ++nt) bv1[nt] = cb1[wn + nt * 16 + lm];
  for (int k0 = 0; k0 < CH1; k0 += 32) {
#pragma unroll
    for (int t = 0; t < 2; ++t) {      // A staging: own Z0 rows + BN0 + ReLU -> As
      int s = t * 256 + tid;
      int r = s >> 2;
      int kc = (s & 3) ^ ((r >> 2) & 3);
      int kg = k0 + kc * 8;
      short8 raw = *(const short8*)(Z0 + (size_t)(bm + r) * CH1 + kg);
      short8 ov;
#pragma unroll
      for (int j = 0; j < 8; ++j) {
        float v = bf2f((unsigned short)raw[j]);
        v = fmaxf(fmaf(v, sa[kg + j], sc[kg + j]), 0.f);
        ov[j] = (short)f2bf(v);
      }
      *(short8*)(As + s * 8) = ov;
    }
#pragma unroll
    for (int t = 0; t < 2; ++t) {      // B staging (w1T)
      int s = (w * 2 + t) * 64 + lane;
      int r = s >> 2;
      int kc = (s & 3) ^ ((r >> 2) & 3);
      const unsigned short* gp = w1T + (size_t)r * CH1 + (k0 + kc * 8);
      __builtin_amdgcn_global_load_lds(
          (const __attribute__((address_space(1))) void*)gp,
          (__attribute__((address_space(3))) void*)(Bs + (w * 2 + t) * 512),
          16, 0, 0);
    }
    __syncthreads();
    {
      short8 af[4], bfr[4];
      int kcl = lane >> 4;
#pragma unroll
      for (int mt = 0; mt < 4; ++mt) {
        int r = wm + mt * 16 + lm;
        int kp = kcl ^ ((r >> 2) & 3);
        af[mt] = *(const short8*)(As + r * 32 + kp * 8);
      }
#pragma unroll
      for (int nt = 0; nt < 4; ++nt) {
        int r = wn + nt * 16 + lm;
        int kp = kcl ^ ((r >> 2) & 3);
        bfr[nt] = *(const short8*)(Bs + r * 32 + kp * 8);
      }
#pragma unroll
      for (int mt = 0; mt < 4; ++mt)
#pragma unroll
        for (int nt = 0; nt < 4; ++nt)
          acc2[mt][nt] = __builtin_amdgcn_mfma_f32_16x16x32_bf16(af[mt], bfr[nt], acc2[mt][nt], 0, 0, 0);
    }
    __syncthreads();
  }
  // BN1 stats on bf16-rounded (acc2 + bv1); z stays in registers — no store
  {
    float ps[4] = {}, pq[4] = {};
#pragma unroll
    for (int mt = 0; mt < 4; ++mt)
#pragma unroll
      for (int nt = 0; nt < 4; ++nt)
#pragma unroll
        for (int r4 = 0; r4 < 4; ++r4) {
          float vr = bf2f(f2bf(acc2[mt][nt][r4] + bv1[nt]));
          ps[nt] += vr; pq[nt] += vr * vr;
        }
    float* colsum = (float*)As;
    float* colsq  = colsum + 128;
    if (tid < 128) { colsum[tid] = 0.f; colsq[tid] = 0.f; }
    __syncthreads();
#pragma unroll
    for (int nt = 0; nt < 4; ++nt) {
      float s = ps[nt], q = pq[nt];
      s += __shfl_down(s, 32); s += __shfl_down(s, 16);
      q += __shfl_down(q, 32); q += __shfl_down(q, 16);
      if (lq == 0) {
        atomicAdd(&colsum[wn + nt * 16 + lm], s);
        atomicAdd(&colsq [wn + nt * 16 + lm], q);
      }
    }
    __syncthreads();
    if (tid < 128) {
      atomicAdd(&sum1[tid], colsum[tid]);
      atomicAdd(&sq1 [tid], colsq[tid]);
    }
  }
  // ---- global barrier 1 ----
  __syncthreads();
  if (tid == 0) {
    __threadfence();
    atomicAdd(&bar[1], 1u);
    while (atomicAdd(&bar[1], 0u) < NBLK) __builtin_amdgcn_s_sleep(8);
  }
  __syncthreads();

  // ===== Phase C: out = relu(BN1(z)) fp32, straight from registers =====
  {
    int bq = bm >> 13;                   // batch (bm multiple of 128)
    int nb0 = (bm & (NN - 1)) + wm + lq * 4;
#pragma unroll
    for (int nt = 0; nt < 4; ++nt) {
      int ch = wn + nt * 16 + lm;
      float mu = atomicAdd(&sum1[ch], 0.f) * invR;       // coherent read
      float var = atomicAdd(&sq1[ch], 0.f) * invR - mu * mu;
      float a = s1[ch] * (1.0f / sqrtf(var + 1e-5f));
      float c = bb1[ch] - mu * a;
#pragma unroll
      for (int mt = 0; mt < 4; ++mt) {
        int nn = nb0 + mt * 16;
        floatx4 o;
#pragma unroll
        for (int r4 = 0; r4 < 4; ++r4) {
          float vr = bf2f(f2bf(acc2[mt][nt][r4] + bv1[nt]));
          o[r4] = fmaxf(fmaf(vr, a, c), 0.f);
        }
        *(floatx4*)(out + (((size_t)(bq * CH2 + ch)) << 13) + nn) = o;
      }
    }
  }
}

extern "C" void kernel_launch(void* const* d_in, const int* in_sizes, int n_in,
                              void* d_out, int out_size, void* d_ws, size_t ws_size,
                              hipStream_t stream) {
  const float* xyz1    = (const float*)d_in[0];
  const float* xyz2    = (const float*)d_in[1];
  const float* points1 = (const float*)d_in[2];
  const float* points2 = (const float*)d_in[3];
  const float* w0  = (const float*)d_in[4];
  const float* cb0 = (const float*)d_in[5];
  const float* s0  = (const float*)d_in[6];
  const float* bb0 = (const float*)d_in[7];
  const float* w1  = (const float*)d_in[8];
  const float* cb1 = (const float*)d_in[9];
  const float* s1  = (const float*)d_in[10];
  const float* bb1 = (const float*)d_in[11];

  float* ws = (float*)d_ws;
  // layout (float units; all 16B-aligned)
  float*          p2t  = ws;                               // 2,097,152
  unsigned short* H0   = (unsigned short*)(ws + 2097152);  // R*192 bf16
  unsigned short* Z0   = (unsigned short*)(ws + 8388608);  // R*256 bf16
  unsigned short* w0T  = (unsigned short*)(ws + 20971520); //    24,576
  unsigned short* w1T  = (unsigned short*)(ws + 20996096); //    16,384
  float*          stats= ws + 21012480;                    // 768 + 2 barrier ctrs

  // 1: transposes + weight cvt + stats/ctr zero (all independent)
  prep<<<2129, 256, 0, stream>>>(points2, p2t, w0, w0T, w1, w1T, stats);

  // 2: 3-NN + interp + H0 build (fused), 8 waves/block
  knn3_gather<<<RTOT / 64, 512, 0, stream>>>(xyz1, xyz2, points1, p2t, H0);

  // 3: fused gemm0 + BN0 + gemm1 + BN1 + ReLU + fp32 out (software global barriers)
  mlp_fused<<<NBLK, 256, 0, stream>>>(H0, w0T, cb0, w1T, cb1,
                                      s0, bb0, s1, bb1, stats, Z0, (float*)d_out);
}

// Round 9
// 269.092 us; speedup vs baseline: 3.0290x; 3.0290x over previous
//
#include <hip/hip_runtime.h>

#define BB 8
#define NN 8192
#define SS 2048
#define DD1 64
#define DD2 128
#define CIN 192
#define CH1 256
#define CH2 128
#define RTOT (BB*NN)   // 65536
#define KCHUNK 256
#define NCHK 8
#define NBLK 512       // fused-MLP grid; co-residency guaranteed (see launch_bounds note)

typedef __attribute__((ext_vector_type(8))) short short8;
typedef __attribute__((ext_vector_type(4))) short shortx4;
typedef __attribute__((ext_vector_type(4))) float floatx4;
typedef __attribute__((ext_vector_type(4))) unsigned uintx4;

__device__ __forceinline__ unsigned short f2bf(float f) {
  unsigned u = __float_as_uint(f);
  u += 0x7fff + ((u >> 16) & 1);   // round-to-nearest-even
  return (unsigned short)(u >> 16);
}
__device__ __forceinline__ float bf2f(unsigned short h) {
  return __uint_as_float(((unsigned)h) << 16);
}

// ---------- fused prep: p2t transpose (2048 blks) + w0T (48) + w1T (32) + stats/ctr zero (1) ----------
__global__ __launch_bounds__(256) void prep(const float* __restrict__ points2, float* __restrict__ p2t,
                                            const float* __restrict__ w0, unsigned short* __restrict__ w0T,
                                            const float* __restrict__ w1, unsigned short* __restrict__ w1T,
                                            float* __restrict__ stats) {
  __shared__ float tile[32][33];
  int blk = blockIdx.x, tid = threadIdx.x;
  int tx = tid & 31, ty = tid >> 5;
  if (blk < 2048) {          // points2 [B][128][S] -> p2t [B][S][128]
    int z = blk >> 8, rem = blk & 255;
    int gy = rem >> 6, gx = rem & 63;
    const float* src = points2 + (size_t)z * DD2 * SS;
    float* dst = p2t + (size_t)z * DD2 * SS;
    int c0 = gx * 32, r0 = gy * 32;
    for (int i = ty; i < 32; i += 8)
      tile[i][tx] = src[(size_t)(r0 + i) * SS + (c0 + tx)];
    __syncthreads();
    for (int i = ty; i < 32; i += 8)
      dst[(size_t)(c0 + i) * DD2 + (r0 + tx)] = tile[tx][i];
  } else if (blk < 2096) {   // w0 [192][256] -> w0T [256][192] bf16
    int r = blk - 2048;
    int gy = r >> 3, gx = r & 7;
    int c0 = gx * 32, r0 = gy * 32;
    for (int i = ty; i < 32; i += 8)
      tile[i][tx] = w0[(size_t)(r0 + i) * CH1 + (c0 + tx)];
    __syncthreads();
    for (int i = ty; i < 32; i += 8)
      w0T[(size_t)(c0 + i) * CIN + (r0 + tx)] = f2bf(tile[tx][i]);
  } else if (blk < 2128) {   // w1 [256][128] -> w1T [128][256] bf16
    int r = blk - 2096;
    int gy = r >> 2, gx = r & 3;
    int c0 = gx * 32, r0 = gy * 32;
    for (int i = ty; i < 32; i += 8)
      tile[i][tx] = w1[(size_t)(r0 + i) * CH2 + (c0 + tx)];
    __syncthreads();
    for (int i = ty; i < 32; i += 8)
      w1T[(size_t)(c0 + i) * CH1 + (r0 + tx)] = f2bf(tile[tx][i]);
  } else {
    // stats[0..767] + 2x {counter,flag} barrier words (re-zeroed every graph replay)
    for (int i = tid; i < 776; i += 256) stats[i] = 0.f;
  }
}

// ---------- fused 3-NN + H0 build (512 threads = 8 waves/block) — unchanged from r5 ----------
__global__ __launch_bounds__(512) void knn3_gather(const float* __restrict__ xyz1,
                                                   const float* __restrict__ xyz2,
                                                   const float* __restrict__ points1,
                                                   const float* __restrict__ p2t,
                                                   unsigned short* __restrict__ H0) {
  __shared__ __align__(16) union LU {
    float coords[4][SS];     // 32 KB: x,y,z,|x|^2 — phases A-C
    float p1t[64][65];       // 16.6 KB, phases D-E (coords dead)
  } u;
  __shared__ __align__(16) unsigned ck[NCHK][64][4];   // 8 KB; tail reused post-rescore
  int* ldsI   = (int*)&ck[0][0][0];          // [64][3] — aliases ck, written after barrier
  float* ldsW = (float*)&ck[0][0][0] + 192;  // [64][3]
  int tid = threadIdx.x;
  int r0 = blockIdx.x * 64;
  int b = r0 >> 13;                 // N = 8192
  int n0 = r0 & (NN - 1);
  const float* x2 = xyz2 + (size_t)b * 3 * SS;
  for (int i = tid; i < SS; i += 512) {
    float xv = x2[i], yv = x2[SS + i], zv = x2[2 * SS + i];
    u.coords[0][i] = xv;
    u.coords[1][i] = yv;
    u.coords[2][i] = zv;
    u.coords[3][i] = xv * xv + yv * yv + zv * zv;
  }
  __syncthreads();
  int row = tid & 63, chk = tid >> 6;   // chunk wave-uniform -> LDS broadcasts
  int n = n0 + row;
  const float* x1 = xyz1 + (size_t)b * 3 * NN;
  float px = x1[n], py = x1[NN + n], pz = x1[2 * NN + n];
  float qx = -2.f * px, qy = -2.f * py, qz = -2.f * pz;
  float pp = px * px + py * py + pz * pz;
  floatx4 qx4 = {qx, qx, qx, qx}, qy4 = {qy, qy, qy, qy};
  floatx4 qz4 = {qz, qz, qz, qz}, pp4 = {pp, pp, pp, pp};
  unsigned c0 = 0xFFFFFFFFu, c1 = 0xFFFFFFFFu, c2 = 0xFFFFFFFFu, c3 = 0xFFFFFFFFu;
  int sbeg = (int)__builtin_amdgcn_readfirstlane((unsigned)(chk * KCHUNK));
#pragma unroll 2
  for (int s8 = sbeg; s8 < sbeg + KCHUNK; s8 += 8) {
#pragma unroll
    for (int p = 0; p < 2; ++p) {
      floatx4 xv = *(const floatx4*)&u.coords[0][s8 + 4 * p];
      floatx4 yv = *(const floatx4*)&u.coords[1][s8 + 4 * p];
      floatx4 zv = *(const floatx4*)&u.coords[2][s8 + 4 * p];
      floatx4 wv = *(const floatx4*)&u.coords[3][s8 + 4 * p];
      floatx4 d = xv * qx4 + wv;        // fma
      d = yv * qy4 + d;                 // fma
      d = zv * qz4 + d;                 // fma
      d = d + pp4;                      // add; d >= 0 (exact-ish |p-x|^2)
#pragma unroll
      for (int e = 0; e < 4; ++e) {
        unsigned k = (__float_as_uint(d[e]) & 0xFFFFF800u) | (unsigned)(s8 + 4 * p + e);
        // sorted top-4 insert via order statistics: new ci = med3(c[i-1], ci, k)
        unsigned m1, m2, m3;
        asm("v_med3_u32 %0, %1, %2, %3" : "=v"(m1) : "v"(c0), "v"(c1), "v"(k));
        asm("v_med3_u32 %0, %1, %2, %3" : "=v"(m2) : "v"(c1), "v"(c2), "v"(k));
        asm("v_med3_u32 %0, %1, %2, %3" : "=v"(m3) : "v"(c2), "v"(c3), "v"(k));
        c0 = __builtin_elementwise_min(c0, k);   // v_min_u32
        c1 = m1; c2 = m2; c3 = m3;
      }
    }
  }
  *(uintx4*)&ck[chk][row][0] = (uintx4){c0, c1, c2, c3};
  // prefetch the p1 tile into registers: latency hides under the rescore
  floatx4 pv[2];
  const float* p1 = points1 + (size_t)b * DD1 * NN;
#pragma unroll
  for (int t = 0; t < 2; ++t) {
    int i = tid + t * 512;             // 0..1023 = 64ch x 16 float4
    int ch = i >> 4, q = i & 15;
    pv[t] = *(const floatx4*)(p1 + (size_t)ch * NN + n0 + q * 4);
  }
  __syncthreads();
  // rescore into registers (reads u.coords + ck; no LDS writes yet)
  int j0, j1, j2; float fw0, fw1, fw2;
  if (tid < 64) {
    float qpx = x1[n0 + tid], qpy = x1[NN + n0 + tid], qpz = x1[2 * NN + n0 + tid];
    double e0 = 1e300, e1 = 1e300, e2 = 1e300;
    j0 = 0x7fffffff; j1 = 0x7fffffff; j2 = 0x7fffffff;
#pragma unroll
    for (int c = 0; c < NCHK; ++c)
#pragma unroll
      for (int t = 0; t < 4; ++t) {
        int si = (int)(ck[c][tid][t] & 0x7FFu);
        double dx = (double)u.coords[0][si] - (double)qpx;
        double dy = (double)u.coords[1][si] - (double)qpy;
        double dz = (double)u.coords[2][si] - (double)qpz;
        double d = dx * dx + dy * dy + dz * dz;
        if (d < e2 || (d == e2 && si < j2)) {
          if (d < e1 || (d == e1 && si < j1)) {
            e2 = e1; j2 = j1;
            if (d < e0 || (d == e0 && si < j0)) { e1 = e0; j1 = j0; e0 = d; j0 = si; }
            else                                { e1 = d;  j1 = si; }
          } else { e2 = d; j2 = si; }
        }
      }
    double rr0 = 1.0 / (e0 + 1e-8), rr1 = 1.0 / (e1 + 1e-8), rr2 = 1.0 / (e2 + 1e-8);
    double sw = rr0 + rr1 + rr2;
    fw0 = (float)(rr0 / sw); fw1 = (float)(rr1 / sw); fw2 = (float)(rr2 / sw);
  }
  __syncthreads();                      // all ck/coords reads done; aliased regions now writable
#pragma unroll
  for (int t = 0; t < 2; ++t) {         // p1t stores (coords region dead)
    int i = tid + t * 512;
    int ch = i >> 4, q = i & 15;
    u.p1t[ch][q * 4 + 0] = pv[t][0];    // component stores: [64][65] stays 2-way max
    u.p1t[ch][q * 4 + 1] = pv[t][1];
    u.p1t[ch][q * 4 + 2] = pv[t][2];
    u.p1t[ch][q * 4 + 3] = pv[t][3];
  }
  if (tid < 64) {                       // ldsI/ldsW into ck's (consumed) region
    ldsI[tid * 3 + 0] = j0; ldsI[tid * 3 + 1] = j1; ldsI[tid * 3 + 2] = j2;
    ldsW[tid * 3 + 0] = fw0; ldsW[tid * 3 + 1] = fw1; ldsW[tid * 3 + 2] = fw2;
  }
  __syncthreads();
  const float* base = p2t + (size_t)b * SS * DD2;
  unsigned short* Hrow = H0 + (size_t)r0 * CIN;
  for (int i = tid; i < 64 * 48; i += 512) {   // quad-columns: 48 per row
    int rr = i / 48;
    int qc = i - rr * 48;
    floatx4 v;
    if (qc < 16) {
      v[0] = u.p1t[qc * 4 + 0][rr];
      v[1] = u.p1t[qc * 4 + 1][rr];
      v[2] = u.p1t[qc * 4 + 2][rr];
      v[3] = u.p1t[qc * 4 + 3][rr];
    } else {
      int cc = qc * 4 - DD1;
      floatx4 g0 = *(const floatx4*)(base + (size_t)ldsI[rr * 3 + 0] * DD2 + cc);
      floatx4 g1 = *(const floatx4*)(base + (size_t)ldsI[rr * 3 + 1] * DD2 + cc);
      floatx4 g2 = *(const floatx4*)(base + (size_t)ldsI[rr * 3 + 2] * DD2 + cc);
      float w0 = ldsW[rr * 3 + 0], w1 = ldsW[rr * 3 + 1], w2 = ldsW[rr * 3 + 2];
#pragma unroll
      for (int e = 0; e < 4; ++e)
        v[e] = w0 * g0[e] + w1 * g1[e] + w2 * g2[e];
    }
    shortx4 pk;
#pragma unroll
    for (int e = 0; e < 4; ++e) pk[e] = (short)f2bf(v[e]);
    *(shortx4*)(Hrow + (size_t)rr * CIN + qc * 4) = pk;   // 8B coalesced stores
  }
}

// ---------- fused MLP: gemm0 -> gbar -> gemm1 (acc in regs) -> gbar -> BN1+ReLU out ----------
// r8 lesson: atomicAdd-as-read is a contended RMW (exclusive line ownership across
// XCDs) — 1.3M of them cost ~670us. This round: arrival = ONE fetch_add per block;
// poll + all stats reads = RELAXED AGENT-SCOPE LOADS (coherent, no ownership, no
// invalidate); one acquire load on barrier exit. Z0 rows written AND read by the
// SAME block. Deadlock-safe: launch_bounds(256,2) + LDS 18KB -> all 512 co-resident.
__global__ __launch_bounds__(256, 2) void mlp_fused(
    const unsigned short* __restrict__ H0,
    const unsigned short* __restrict__ w0T, const float* __restrict__ cb0,
    const unsigned short* __restrict__ w1T, const float* __restrict__ cb1,
    const float* __restrict__ s0, const float* __restrict__ bb0,
    const float* __restrict__ s1, const float* __restrict__ bb1,
    float* __restrict__ stats, unsigned short* __restrict__ Z0,
    float* __restrict__ out)
{
  __shared__ __align__(16) unsigned short As[128 * 32];
  __shared__ __align__(16) unsigned short Bs[128 * 32];
  __shared__ float sa[256];
  __shared__ float sc[256];
  float* sum0 = stats;       float* sq0 = stats + 256;
  float* sum1 = stats + 512; float* sq1 = stats + 640;
  unsigned* bar = (unsigned*)(stats + 768);    // [ctr0,flag0,ctr1,flag1], prep-zeroed
  int tid = threadIdx.x;
  int lane = tid & 63, w = tid >> 6;
  int wm = (w & 1) << 6, wn = (w >> 1) << 6;
  int lm = lane & 15, lq = lane >> 4;
  int bm = blockIdx.x << 7;
  const float invR = 1.0f / RTOT;

  // ===== Phase A: Z0 = H0 @ w0T + cb0, two bn-halves sequentially =====
  for (int half = 0; half < 2; ++half) {
    int bn = half << 7;
    __syncthreads();                 // As free (prev half's colsum reads done)
    floatx4 acc[4][4] = {};
    for (int k0 = 0; k0 < CIN; k0 += 32) {
#pragma unroll
      for (int t = 0; t < 2; ++t) {  // A staging (H0) via global_load_lds
        int s = (w * 2 + t) * 64 + lane;
        int r = s >> 2;
        int kc = (s & 3) ^ ((r >> 2) & 3);
        const unsigned short* gp = H0 + (size_t)(bm + r) * CIN + (k0 + kc * 8);
        __builtin_amdgcn_global_load_lds(
            (const __attribute__((address_space(1))) void*)gp,
            (__attribute__((address_space(3))) void*)(As + (w * 2 + t) * 512),
            16, 0, 0);
      }
#pragma unroll
      for (int t = 0; t < 2; ++t) {  // B staging (w0T)
        int s = (w * 2 + t) * 64 + lane;
        int r = s >> 2;
        int kc = (s & 3) ^ ((r >> 2) & 3);
        const unsigned short* gp = w0T + (size_t)(bn + r) * CIN + (k0 + kc * 8);
        __builtin_amdgcn_global_load_lds(
            (const __attribute__((address_space(1))) void*)gp,
            (__attribute__((address_space(3))) void*)(Bs + (w * 2 + t) * 512),
            16, 0, 0);
      }
      __syncthreads();
      {
        short8 af[4], bfr[4];
        int kcl = lane >> 4;
#pragma unroll
        for (int mt = 0; mt < 4; ++mt) {
          int r = wm + mt * 16 + lm;
          int kp = kcl ^ ((r >> 2) & 3);
          af[mt] = *(const short8*)(As + r * 32 + kp * 8);
        }
#pragma unroll
        for (int nt = 0; nt < 4; ++nt) {
          int r = wn + nt * 16 + lm;
          int kp = kcl ^ ((r >> 2) & 3);
          bfr[nt] = *(const short8*)(Bs + r * 32 + kp * 8);
        }
#pragma unroll
        for (int mt = 0; mt < 4; ++mt)
#pragma unroll
          for (int nt = 0; nt < 4; ++nt)
            acc[mt][nt] = __builtin_amdgcn_mfma_f32_16x16x32_bf16(af[mt], bfr[nt], acc[mt][nt], 0, 0, 0);
      }
      __syncthreads();
    }
    // epilogue: Z0 store + column stats
    float bv[4];
#pragma unroll
    for (int nt = 0; nt < 4; ++nt) bv[nt] = cb0[bn + wn + nt * 16 + lm];
    float ps[4] = {}, pq[4] = {};
#pragma unroll
    for (int mt = 0; mt < 4; ++mt)
#pragma unroll
      for (int r4 = 0; r4 < 4; ++r4) {
        int rowg = bm + wm + mt * 16 + lq * 4 + r4;
        unsigned short* cp = Z0 + (size_t)rowg * CH1 + bn + wn + lm;
#pragma unroll
        for (int nt = 0; nt < 4; ++nt) {
          unsigned short us = f2bf(acc[mt][nt][r4] + bv[nt]);
          cp[nt * 16] = us;
          float vr = bf2f(us);           // stats on the bf16-rounded stored value
          ps[nt] += vr; pq[nt] += vr * vr;
        }
      }
    float* colsum = (float*)As;          // reuse LDS (all waves past last barrier)
    float* colsq  = colsum + 128;
    if (tid < 128) { colsum[tid] = 0.f; colsq[tid] = 0.f; }
    __syncthreads();
#pragma unroll
    for (int nt = 0; nt < 4; ++nt) {
      float s = ps[nt], q = pq[nt];
      s += __shfl_down(s, 32); s += __shfl_down(s, 16);
      q += __shfl_down(q, 32); q += __shfl_down(q, 16);
      if (lq == 0) {
        atomicAdd(&colsum[wn + nt * 16 + lm], s);
        atomicAdd(&colsq [wn + nt * 16 + lm], q);
      }
    }
    __syncthreads();
    if (tid < 128) {
      atomicAdd(&sum0[bn + tid], colsum[tid]);
      atomicAdd(&sq0 [bn + tid], colsq[tid]);
    }
  }
  // ---- global barrier 0: one RMW arrival/block, relaxed-load polling ----
  __syncthreads();
  if (tid == 0) {
    unsigned old = __hip_atomic_fetch_add(&bar[0], 1u, __ATOMIC_ACQ_REL,
                                          __HIP_MEMORY_SCOPE_AGENT);
    if (old == NBLK - 1) {
      __hip_atomic_store(&bar[1], 1u, __ATOMIC_RELEASE, __HIP_MEMORY_SCOPE_AGENT);
    } else {
      while (__hip_atomic_load(&bar[1], __ATOMIC_RELAXED, __HIP_MEMORY_SCOPE_AGENT) == 0u)
        __builtin_amdgcn_s_sleep(16);
      (void)__hip_atomic_load(&bar[1], __ATOMIC_ACQUIRE, __HIP_MEMORY_SCOPE_AGENT);
    }
  }
  __syncthreads();

  // ===== Phase B: acc2 = relu(BN0(Z0)) @ w1T + cb1 (bn = 0, K = 256) =====
  for (int i = tid; i < CH1; i += 256) {
    float su = __hip_atomic_load(&sum0[i], __ATOMIC_RELAXED, __HIP_MEMORY_SCOPE_AGENT);
    float qv = __hip_atomic_load(&sq0[i],  __ATOMIC_RELAXED, __HIP_MEMORY_SCOPE_AGENT);
    float mu = su * invR;
    float var = qv * invR - mu * mu;
    float aa = s0[i] * (1.0f / sqrtf(var + 1e-5f));
    sa[i] = aa; sc[i] = bb0[i] - mu * aa;
  }
  __syncthreads();
  floatx4 acc2[4][4] = {};
  float bv1[4];
#pragma unroll
  for (int nt = 0; nt < 4; ++nt) bv1[nt] = cb1[wn + nt * 16 + lm];
  for (int k0 = 0; k0 < CH1; k0 += 32) {
#pragma unroll
    for (int t = 0; t < 2; ++t) {      // A staging: own Z0 rows + BN0 + ReLU -> As
      int s = t * 256 + tid;
      int r = s >> 2;
      int kc = (s & 3) ^ ((r >> 2) & 3);
      int kg = k0 + kc * 8;
      short8 raw = *(const short8*)(Z0 + (size_t)(bm + r) * CH1 + kg);
      short8 ov;
#pragma unroll
      for (int j = 0; j < 8; ++j) {
        float v = bf2f((unsigned short)raw[j]);
        v = fmaxf(fmaf(v, sa[kg + j], sc[kg + j]), 0.f);
        ov[j] = (short)f2bf(v);
      }
      *(short8*)(As + s * 8) = ov;
    }
#pragma unroll
    for (int t = 0; t < 2; ++t) {      // B staging (w1T)
      int s = (w * 2 + t) * 64 + lane;
      int r = s >> 2;
      int kc = (s & 3) ^ ((r >> 2) & 3);
      const unsigned short* gp = w1T + (size_t)r * CH1 + (k0 + kc * 8);
      __builtin_amdgcn_global_load_lds(
          (const __attribute__((address_space(1))) void*)gp,
          (__attribute__((address_space(3))) void*)(Bs + (w * 2 + t) * 512),
          16, 0, 0);
    }
    __syncthreads();
    {
      short8 af[4], bfr[4];
      int kcl = lane >> 4;
#pragma unroll
      for (int mt = 0; mt < 4; ++mt) {
        int r = wm + mt * 16 + lm;
        int kp = kcl ^ ((r >> 2) & 3);
        af[mt] = *(const short8*)(As + r * 32 + kp * 8);
      }
#pragma unroll
      for (int nt = 0; nt < 4; ++nt) {
        int r = wn + nt * 16 + lm;
        int kp = kcl ^ ((r >> 2) & 3);
        bfr[nt] = *(const short8*)(Bs + r * 32 + kp * 8);
      }
#pragma unroll
      for (int mt = 0; mt < 4; ++mt)
#pragma unroll
        for (int nt = 0; nt < 4; ++nt)
          acc2[mt][nt] = __builtin_amdgcn_mfma_f32_16x16x32_bf16(af[mt], bfr[nt], acc2[mt][nt], 0, 0, 0);
    }
    __syncthreads();
  }
  // BN1 stats on bf16-rounded (acc2 + bv1); z stays in registers — no store
  {
    float ps[4] = {}, pq[4] = {};
#pragma unroll
    for (int mt = 0; mt < 4; ++mt)
#pragma unroll
      for (int nt = 0; nt < 4; ++nt)
#pragma unroll
        for (int r4 = 0; r4 < 4; ++r4) {
          float vr = bf2f(f2bf(acc2[mt][nt][r4] + bv1[nt]));
          ps[nt] += vr; pq[nt] += vr * vr;
        }
    float* colsum = (float*)As;
    float* colsq  = colsum + 128;
    if (tid < 128) { colsum[tid] = 0.f; colsq[tid] = 0.f; }
    __syncthreads();
#pragma unroll
    for (int nt = 0; nt < 4; ++nt) {
      float s = ps[nt], q = pq[nt];
      s += __shfl_down(s, 32); s += __shfl_down(s, 16);
      q += __shfl_down(q, 32); q += __shfl_down(q, 16);
      if (lq == 0) {
        atomicAdd(&colsum[wn + nt * 16 + lm], s);
        atomicAdd(&colsq [wn + nt * 16 + lm], q);
      }
    }
    __syncthreads();
    if (tid < 128) {
      atomicAdd(&sum1[tid], colsum[tid]);
      atomicAdd(&sq1 [tid], colsq[tid]);
    }
  }
  // ---- global barrier 1 ----
  __syncthreads();
  if (tid == 0) {
    unsigned old = __hip_atomic_fetch_add(&bar[2], 1u, __ATOMIC_ACQ_REL,
                                          __HIP_MEMORY_SCOPE_AGENT);
    if (old == NBLK - 1) {
      __hip_atomic_store(&bar[3], 1u, __ATOMIC_RELEASE, __HIP_MEMORY_SCOPE_AGENT);
    } else {
      while (__hip_atomic_load(&bar[3], __ATOMIC_RELAXED, __HIP_MEMORY_SCOPE_AGENT) == 0u)
        __builtin_amdgcn_s_sleep(16);
      (void)__hip_atomic_load(&bar[3], __ATOMIC_ACQUIRE, __HIP_MEMORY_SCOPE_AGENT);
    }
  }
  __syncthreads();

  // ===== Phase C: BN1 coeffs once per block into LDS, then out = relu(BN1(z)) fp32 =====
  for (int i = tid; i < CH2; i += 256) {
    float su = __hip_atomic_load(&sum1[i], __ATOMIC_RELAXED, __HIP_MEMORY_SCOPE_AGENT);
    float qv = __hip_atomic_load(&sq1[i],  __ATOMIC_RELAXED, __HIP_MEMORY_SCOPE_AGENT);
    float mu = su * invR;
    float var = qv * invR - mu * mu;
    float a = s1[i] * (1.0f / sqrtf(var + 1e-5f));
    sa[i] = a; sc[i] = bb1[i] - mu * a;
  }
  __syncthreads();
  {
    int bq = bm >> 13;                   // batch (bm multiple of 128)
    int nb0 = (bm & (NN - 1)) + wm + lq * 4;
#pragma unroll
    for (int nt = 0; nt < 4; ++nt) {
      int ch = wn + nt * 16 + lm;
      float a = sa[ch], c = sc[ch];
#pragma unroll
      for (int mt = 0; mt < 4; ++mt) {
        int nn = nb0 + mt * 16;
        floatx4 o;
#pragma unroll
        for (int r4 = 0; r4 < 4; ++r4) {
          float vr = bf2f(f2bf(acc2[mt][nt][r4] + bv1[nt]));
          o[r4] = fmaxf(fmaf(vr, a, c), 0.f);
        }
        *(floatx4*)(out + (((size_t)(bq * CH2 + ch)) << 13) + nn) = o;
      }
    }
  }
}

extern "C" void kernel_launch(void* const* d_in, const int* in_sizes, int n_in,
                              void* d_out, int out_size, void* d_ws, size_t ws_size,
                              hipStream_t stream) {
  const float* xyz1    = (const float*)d_in[0];
  const float* xyz2    = (const float*)d_in[1];
  const float* points1 = (const float*)d_in[2];
  const float* points2 = (const float*)d_in[3];
  const float* w0  = (const float*)d_in[4];
  const float* cb0 = (const float*)d_in[5];
  const float* s0  = (const float*)d_in[6];
  const float* bb0 = (const float*)d_in[7];
  const float* w1  = (const float*)d_in[8];
  const float* cb1 = (const float*)d_in[9];
  const float* s1  = (const float*)d_in[10];
  const float* bb1 = (const float*)d_in[11];

  float* ws = (float*)d_ws;
  // layout (float units; all 16B-aligned)
  float*          p2t  = ws;                               // 2,097,152
  unsigned short* H0   = (unsigned short*)(ws + 2097152);  // R*192 bf16
  unsigned short* Z0   = (unsigned short*)(ws + 8388608);  // R*256 bf16
  unsigned short* w0T  = (unsigned short*)(ws + 20971520); //    24,576
  unsigned short* w1T  = (unsigned short*)(ws + 20996096); //    16,384
  float*          stats= ws + 21012480;                    // 768 + 4 barrier words

  // 1: transposes + weight cvt + stats/ctr zero (all independent)
  prep<<<2129, 256, 0, stream>>>(points2, p2t, w0, w0T, w1, w1T, stats);

  // 2: 3-NN + interp + H0 build (fused), 8 waves/block
  knn3_gather<<<RTOT / 64, 512, 0, stream>>>(xyz1, xyz2, points1, p2t, H0);

  // 3: fused gemm0 + BN0 + gemm1 + BN1 + ReLU + fp32 out (software global barriers)
  mlp_fused<<<NBLK, 256, 0, stream>>>(H0, w0T, cb0, w1T, cb1,
                                      s0, bb0, s1, bb1, stats, Z0, (float*)d_out);
}

// Round 10
// 209.918 us; speedup vs baseline: 3.8828x; 1.2819x over previous
//
#include <hip/hip_runtime.h>

#define BB 8
#define NN 8192
#define SS 2048
#define DD1 64
#define DD2 128
#define CIN 192
#define CH1 256
#define CH2 128
#define RTOT (BB*NN)   // 65536
#define KCHUNK 256
#define NCHK 8

typedef __attribute__((ext_vector_type(8))) short short8;
typedef __attribute__((ext_vector_type(4))) short shortx4;
typedef __attribute__((ext_vector_type(4))) float floatx4;
typedef __attribute__((ext_vector_type(4))) unsigned uintx4;

__device__ __forceinline__ unsigned short f2bf(float f) {
  unsigned u = __float_as_uint(f);
  u += 0x7fff + ((u >> 16) & 1);   // round-to-nearest-even
  return (unsigned short)(u >> 16);
}
__device__ __forceinline__ float bf2f(unsigned short h) {
  return __uint_as_float(((unsigned)h) << 16);
}

// ---------- fused prep: p2t transpose (2048 blks) + w0T (48) + w1T (32) + stats zero (1) ----------
__global__ __launch_bounds__(256) void prep(const float* __restrict__ points2, float* __restrict__ p2t,
                                            const float* __restrict__ w0, unsigned short* __restrict__ w0T,
                                            const float* __restrict__ w1, unsigned short* __restrict__ w1T,
                                            float* __restrict__ stats) {
  __shared__ float tile[32][33];
  int blk = blockIdx.x, tid = threadIdx.x;
  int tx = tid & 31, ty = tid >> 5;
  if (blk < 2048) {          // points2 [B][128][S] -> p2t [B][S][128]
    int z = blk >> 8, rem = blk & 255;
    int gy = rem >> 6, gx = rem & 63;
    const float* src = points2 + (size_t)z * DD2 * SS;
    float* dst = p2t + (size_t)z * DD2 * SS;
    int c0 = gx * 32, r0 = gy * 32;
    for (int i = ty; i < 32; i += 8)
      tile[i][tx] = src[(size_t)(r0 + i) * SS + (c0 + tx)];
    __syncthreads();
    for (int i = ty; i < 32; i += 8)
      dst[(size_t)(c0 + i) * DD2 + (r0 + tx)] = tile[tx][i];
  } else if (blk < 2096) {   // w0 [192][256] -> w0T [256][192] bf16
    int r = blk - 2048;
    int gy = r >> 3, gx = r & 7;
    int c0 = gx * 32, r0 = gy * 32;
    for (int i = ty; i < 32; i += 8)
      tile[i][tx] = w0[(size_t)(r0 + i) * CH1 + (c0 + tx)];
    __syncthreads();
    for (int i = ty; i < 32; i += 8)
      w0T[(size_t)(c0 + i) * CIN + (r0 + tx)] = f2bf(tile[tx][i]);
  } else if (blk < 2128) {   // w1 [256][128] -> w1T [128][256] bf16
    int r = blk - 2096;
    int gy = r >> 2, gx = r & 3;
    int c0 = gx * 32, r0 = gy * 32;
    for (int i = ty; i < 32; i += 8)
      tile[i][tx] = w1[(size_t)(r0 + i) * CH2 + (c0 + tx)];
    __syncthreads();
    for (int i = ty; i < 32; i += 8)
      w1T[(size_t)(c0 + i) * CH1 + (r0 + tx)] = f2bf(tile[tx][i]);
  } else {
    for (int i = tid; i < 768; i += 256) stats[i] = 0.f;
  }
}

// ---------- fused 3-NN + interp + GEMM0 (+BN0 stats): one block = 64 rows, sync-free ----------
// r9 lesson: software global barriers cost more than kernel boundaries (137us fused vs
// 81us chain). But gemm0's data dependency is BLOCK-LOCAL: this block's 64 H0 rows are
// exactly one gemm0 M-tile. So phase F does the 64x256 GEMM in-kernel from LDS H:
//  - H0 global buffer eliminated (25MB write + 25MB read)
//  - gemm0 launch + gap eliminated
//  - uses knn3's idle MFMA pipe
// H[64][200] bf16 lives in the coords union (written only after the rescore's last
// coords read). w0T (98KB) is L2-resident across all 1024 blocks. Numerics: H values
// bit-identical to old H0 (same f2bf points); MFMA fragment VALUES identical (the old
// XOR LDS swizzle was value-neutral); stats add-order already non-deterministic.
__global__ __launch_bounds__(512, 4) void knn3_g0(const float* __restrict__ xyz1,
                                                  const float* __restrict__ xyz2,
                                                  const float* __restrict__ points1,
                                                  const float* __restrict__ p2t,
                                                  const unsigned short* __restrict__ w0T,
                                                  const float* __restrict__ cb0,
                                                  float* __restrict__ osum, float* __restrict__ osq,
                                                  unsigned short* __restrict__ Z0) {
  __shared__ __align__(16) union LU {
    float coords[4][SS];           // 32 KB: x,y,z,|x|^2 — phases A-C
    unsigned short H[64][200];     // 25.6 KB: H0 rows (192 cols + 8 pad) — phases D-F
  } u;
  __shared__ __align__(16) unsigned ck[NCHK][64][4];   // 8 KB; tail reused post-rescore
  __shared__ __align__(16) unsigned short Bs[256 * 32]; // 16 KB w0T k-tile
  int* ldsI   = (int*)&ck[0][0][0];          // [64][3] — aliases ck, written after barrier
  float* ldsW = (float*)&ck[0][0][0] + 192;  // [64][3]
  int tid = threadIdx.x;
  int r0 = blockIdx.x * 64;
  int b = r0 >> 13;                 // N = 8192
  int n0 = r0 & (NN - 1);
  const float* x2 = xyz2 + (size_t)b * 3 * SS;
  for (int i = tid; i < SS; i += 512) {
    float xv = x2[i], yv = x2[SS + i], zv = x2[2 * SS + i];
    u.coords[0][i] = xv;
    u.coords[1][i] = yv;
    u.coords[2][i] = zv;
    u.coords[3][i] = xv * xv + yv * yv + zv * zv;
  }
  __syncthreads();
  int row = tid & 63, chk = tid >> 6;   // chunk wave-uniform -> LDS broadcasts
  int n = n0 + row;
  const float* x1 = xyz1 + (size_t)b * 3 * NN;
  float px = x1[n], py = x1[NN + n], pz = x1[2 * NN + n];
  float qx = -2.f * px, qy = -2.f * py, qz = -2.f * pz;
  float pp = px * px + py * py + pz * pz;
  floatx4 qx4 = {qx, qx, qx, qx}, qy4 = {qy, qy, qy, qy};
  floatx4 qz4 = {qz, qz, qz, qz}, pp4 = {pp, pp, pp, pp};
  unsigned c0 = 0xFFFFFFFFu, c1 = 0xFFFFFFFFu, c2 = 0xFFFFFFFFu, c3 = 0xFFFFFFFFu;
  int sbeg = (int)__builtin_amdgcn_readfirstlane((unsigned)(chk * KCHUNK));
#pragma unroll 2
  for (int s8 = sbeg; s8 < sbeg + KCHUNK; s8 += 8) {
#pragma unroll
    for (int p = 0; p < 2; ++p) {
      floatx4 xv = *(const floatx4*)&u.coords[0][s8 + 4 * p];
      floatx4 yv = *(const floatx4*)&u.coords[1][s8 + 4 * p];
      floatx4 zv = *(const floatx4*)&u.coords[2][s8 + 4 * p];
      floatx4 wv = *(const floatx4*)&u.coords[3][s8 + 4 * p];
      floatx4 d = xv * qx4 + wv;        // fma
      d = yv * qy4 + d;                 // fma
      d = zv * qz4 + d;                 // fma
      d = d + pp4;                      // add; d >= 0 (exact-ish |p-x|^2)
#pragma unroll
      for (int e = 0; e < 4; ++e) {
        unsigned k = (__float_as_uint(d[e]) & 0xFFFFF800u) | (unsigned)(s8 + 4 * p + e);
        // sorted top-4 insert via order statistics: new ci = med3(c[i-1], ci, k)
        unsigned m1, m2, m3;
        asm("v_med3_u32 %0, %1, %2, %3" : "=v"(m1) : "v"(c0), "v"(c1), "v"(k));
        asm("v_med3_u32 %0, %1, %2, %3" : "=v"(m2) : "v"(c1), "v"(c2), "v"(k));
        asm("v_med3_u32 %0, %1, %2, %3" : "=v"(m3) : "v"(c2), "v"(c3), "v"(k));
        c0 = __builtin_elementwise_min(c0, k);   // v_min_u32
        c1 = m1; c2 = m2; c3 = m3;
      }
    }
  }
  *(uintx4*)&ck[chk][row][0] = (uintx4){c0, c1, c2, c3};
  // prefetch the p1 tile into registers: latency hides under the rescore
  floatx4 pv[2];
  const float* p1 = points1 + (size_t)b * DD1 * NN;
#pragma unroll
  for (int t = 0; t < 2; ++t) {
    int i = tid + t * 512;             // 0..1023 = 64ch x 16 float4
    int ch = i >> 4, q = i & 15;
    pv[t] = *(const floatx4*)(p1 + (size_t)ch * NN + n0 + q * 4);
  }
  __syncthreads();
  // rescore into registers (reads u.coords + ck; no LDS writes yet)
  int j0, j1, j2; float fw0, fw1, fw2;
  if (tid < 64) {
    float qpx = x1[n0 + tid], qpy = x1[NN + n0 + tid], qpz = x1[2 * NN + n0 + tid];
    double e0 = 1e300, e1 = 1e300, e2 = 1e300;
    j0 = 0x7fffffff; j1 = 0x7fffffff; j2 = 0x7fffffff;
#pragma unroll
    for (int c = 0; c < NCHK; ++c)
#pragma unroll
      for (int t = 0; t < 4; ++t) {
        int si = (int)(ck[c][tid][t] & 0x7FFu);
        double dx = (double)u.coords[0][si] - (double)qpx;
        double dy = (double)u.coords[1][si] - (double)qpy;
        double dz = (double)u.coords[2][si] - (double)qpz;
        double d = dx * dx + dy * dy + dz * dz;
        if (d < e2 || (d == e2 && si < j2)) {
          if (d < e1 || (d == e1 && si < j1)) {
            e2 = e1; j2 = j1;
            if (d < e0 || (d == e0 && si < j0)) { e1 = e0; j1 = j0; e0 = d; j0 = si; }
            else                                { e1 = d;  j1 = si; }
          } else { e2 = d; j2 = si; }
        }
      }
    double rr0 = 1.0 / (e0 + 1e-8), rr1 = 1.0 / (e1 + 1e-8), rr2 = 1.0 / (e2 + 1e-8);
    double sw = rr0 + rr1 + rr2;
    fw0 = (float)(rr0 / sw); fw1 = (float)(rr1 / sw); fw2 = (float)(rr2 / sw);
  }
  __syncthreads();                      // all ck/coords reads done; union region writable
  // phase D': H[:,0:64] = f2bf(p1^T)  (same f2bf values as the old H0 columns)
#pragma unroll
  for (int t = 0; t < 2; ++t) {
    int i = tid + t * 512;
    int ch = i >> 4, q = i & 15;
#pragma unroll
    for (int e = 0; e < 4; ++e)
      u.H[q * 4 + e][ch] = f2bf(pv[t][e]);
  }
  if (tid < 64) {                       // ldsI/ldsW into ck's (consumed) region
    ldsI[tid * 3 + 0] = j0; ldsI[tid * 3 + 1] = j1; ldsI[tid * 3 + 2] = j2;
    ldsW[tid * 3 + 0] = fw0; ldsW[tid * 3 + 1] = fw1; ldsW[tid * 3 + 2] = fw2;
  }
  __syncthreads();
  // phase E': interp -> H[:,64:192]
  const float* base = p2t + (size_t)b * SS * DD2;
  for (int i = tid; i < 64 * 32; i += 512) {   // 32 interp quad-cols per row
    int rr = i >> 5;
    int cc = (i & 31) * 4;
    floatx4 g0 = *(const floatx4*)(base + (size_t)ldsI[rr * 3 + 0] * DD2 + cc);
    floatx4 g1 = *(const floatx4*)(base + (size_t)ldsI[rr * 3 + 1] * DD2 + cc);
    floatx4 g2 = *(const floatx4*)(base + (size_t)ldsI[rr * 3 + 2] * DD2 + cc);
    float w0 = ldsW[rr * 3 + 0], w1 = ldsW[rr * 3 + 1], w2 = ldsW[rr * 3 + 2];
    shortx4 pk;
#pragma unroll
    for (int e = 0; e < 4; ++e)
      pk[e] = (short)f2bf(w0 * g0[e] + w1 * g1[e] + w2 * g2[e]);
    *(shortx4*)&u.H[rr][DD1 + cc] = pk;
  }
  __syncthreads();
  // phase F: Z0[r0..r0+63][0..255] = H @ w0T^T + cb0, + BN0 column stats
  int lane = tid & 63, w = tid >> 6;
  int wn = w << 5;                       // 32 output cols per wave (8 waves x 32 = 256)
  int kcl = lane >> 4, lm = lane & 15, lq = lane >> 4;
  floatx4 acc[4][2] = {};                // [mt][nt]: 4 m-frags x 2 n-frags
  for (int k0 = 0; k0 < CIN; k0 += 32) {
#pragma unroll
    for (int t = 0; t < 2; ++t) {        // stage w0T k-tile (XOR-swizzled like gemm_mfma)
      int s = (w * 2 + t) * 64 + lane;
      int r = s >> 2;
      int kc = (s & 3) ^ ((r >> 2) & 3);
      const unsigned short* gp = w0T + (size_t)r * CIN + (k0 + kc * 8);
      __builtin_amdgcn_global_load_lds(
          (const __attribute__((address_space(1))) void*)gp,
          (__attribute__((address_space(3))) void*)(Bs + (w * 2 + t) * 512),
          16, 0, 0);
    }
    __syncthreads();
    short8 af[4], bfr[2];
#pragma unroll
    for (int mt = 0; mt < 4; ++mt)       // A from H (plain layout, no swizzle needed)
      af[mt] = *(const short8*)&u.H[mt * 16 + lm][k0 + kcl * 8];
#pragma unroll
    for (int nt = 0; nt < 2; ++nt) {
      int r = wn + nt * 16 + lm;
      int kp = kcl ^ ((r >> 2) & 3);
      bfr[nt] = *(const short8*)(Bs + r * 32 + kp * 8);
    }
#pragma unroll
    for (int mt = 0; mt < 4; ++mt)
#pragma unroll
      for (int nt = 0; nt < 2; ++nt)
        acc[mt][nt] = __builtin_amdgcn_mfma_f32_16x16x32_bf16(af[mt], bfr[nt], acc[mt][nt], 0, 0, 0);
    __syncthreads();
  }
  // epilogue: Z0 store (C/D layout col=lane&15, row=(lane>>4)*4+reg) + column stats
  float bv[2];
#pragma unroll
  for (int nt = 0; nt < 2; ++nt) bv[nt] = cb0[wn + nt * 16 + lm];
  float ps[2] = {}, pq[2] = {};
#pragma unroll
  for (int mt = 0; mt < 4; ++mt)
#pragma unroll
    for (int r4 = 0; r4 < 4; ++r4) {
      int rowg = r0 + mt * 16 + lq * 4 + r4;
      unsigned short* cp = Z0 + (size_t)rowg * CH1 + wn + lm;
#pragma unroll
      for (int nt = 0; nt < 2; ++nt) {
        unsigned short us = f2bf(acc[mt][nt][r4] + bv[nt]);
        cp[nt * 16] = us;
        float vr = bf2f(us);             // stats on the bf16-rounded stored value
        ps[nt] += vr; pq[nt] += vr * vr;
      }
    }
#pragma unroll
  for (int nt = 0; nt < 2; ++nt) {       // waves own disjoint cols -> direct global adds
    float s = ps[nt], q = pq[nt];
    s += __shfl_down(s, 32); s += __shfl_down(s, 16);
    q += __shfl_down(q, 32); q += __shfl_down(q, 16);
    if (lq == 0) {
      atomicAdd(&osum[wn + nt * 16 + lm], s);
      atomicAdd(&osq [wn + nt * 16 + lm], q);
    }
  }
}

// ---------- bf16 MFMA GEMM + fused column stats — only BNFUSE=1 TRANSP=1 used now ----------
template<int BNFUSE, int K, int TRANSP>
__global__ __launch_bounds__(256) void gemm_mfma(
    const unsigned short* __restrict__ A,
    const unsigned short* __restrict__ BT,
    const float* __restrict__ bias,
    const float* __restrict__ psum, const float* __restrict__ psq,
    const float* __restrict__ pscale, const float* __restrict__ pbias,
    float* __restrict__ osum, float* __restrict__ osq,
    unsigned short* __restrict__ C, int Nc)
{
  __shared__ __align__(16) unsigned short As[2][128 * 32];
  __shared__ __align__(16) unsigned short Bs[2][128 * 32];
  __shared__ float sa[BNFUSE ? 256 : 1];
  __shared__ float sc[BNFUSE ? 256 : 1];
  int tid = threadIdx.x;
  int lane = tid & 63, w = tid >> 6;
  int bn = blockIdx.x << 7, bm = blockIdx.y << 7;
  int wm = (w & 1) << 6, wn = (w >> 1) << 6;
  if (BNFUSE) {
    const float invR = 1.0f / RTOT;
    for (int i = tid; i < K; i += 256) {
      float mu = psum[i] * invR;
      float var = psq[i] * invR - mu * mu;
      float aa = pscale[i] * (1.0f / sqrtf(var + 1e-5f));
      sa[i] = aa; sc[i] = pbias[i] - mu * aa;
    }
    __syncthreads();
  }
  floatx4 acc[4][4] = {};   // [mt][nt]

  auto stageB = [&](int buf, int k0) {
#pragma unroll
    for (int t = 0; t < 2; ++t) {
      int s = (w * 2 + t) * 64 + lane;
      int r = s >> 2;
      int kc = (s & 3) ^ ((r >> 2) & 3);
      const unsigned short* gp = BT + (size_t)(bn + r) * K + (k0 + kc * 8);
      __builtin_amdgcn_global_load_lds(
          (const __attribute__((address_space(1))) void*)gp,
          (__attribute__((address_space(3))) void*)(Bs[buf] + (w * 2 + t) * 512),
          16, 0, 0);
    }
  };
  auto stageA_lds = [&](int buf, int k0) {
#pragma unroll
    for (int t = 0; t < 2; ++t) {
      int s = (w * 2 + t) * 64 + lane;
      int r = s >> 2;
      int kc = (s & 3) ^ ((r >> 2) & 3);
      const unsigned short* gp = A + (size_t)(bm + r) * K + (k0 + kc * 8);
      __builtin_amdgcn_global_load_lds(
          (const __attribute__((address_space(1))) void*)gp,
          (__attribute__((address_space(3))) void*)(As[buf] + (w * 2 + t) * 512),
          16, 0, 0);
    }
  };
  auto procA = [&](int buf, int k0, short8* raw) {
#pragma unroll
    for (int t = 0; t < 2; ++t) {
      int s = t * 256 + tid;
      int r = s >> 2;
      int kc = (s & 3) ^ ((r >> 2) & 3);
      int kg = k0 + kc * 8;
      short8 ov;
#pragma unroll
      for (int j = 0; j < 8; ++j) {
        float v = bf2f((unsigned short)raw[t][j]);
        v = fmaxf(fmaf(v, sa[kg + j], sc[kg + j]), 0.f);
        ov[j] = (short)f2bf(v);
      }
      *(short8*)(As[buf] + s * 8) = ov;
    }
  };

  // prologue: fill buffer 0
  if (!BNFUSE) {
    stageA_lds(0, 0);
  } else {
    short8 raw[2];
#pragma unroll
    for (int t = 0; t < 2; ++t) {
      int s = t * 256 + tid;
      int r = s >> 2;
      int kc = (s & 3) ^ ((r >> 2) & 3);
      raw[t] = *(const short8*)(A + (size_t)(bm + r) * K + (kc * 8));
    }
    procA(0, 0, raw);
  }
  stageB(0, 0);
  __syncthreads();

  int cur = 0;
  for (int k0 = 0; k0 < K; k0 += 32) {
    int nk = k0 + 32;
    short8 raw[2];
    if (nk < K) {              // issue next tile's loads before computing current
      if (!BNFUSE) {
        stageA_lds(cur ^ 1, nk);
      } else {
#pragma unroll
        for (int t = 0; t < 2; ++t) {
          int s = t * 256 + tid;
          int r = s >> 2;
          int kc = (s & 3) ^ ((r >> 2) & 3);
          raw[t] = *(const short8*)(A + (size_t)(bm + r) * K + (nk + kc * 8));
        }
      }
      stageB(cur ^ 1, nk);
    }
    // compute current buffer
    {
      short8 af[4], bfr[4];
      int kcl = lane >> 4;
      int lm = lane & 15;
#pragma unroll
      for (int mt = 0; mt < 4; ++mt) {
        int r = wm + mt * 16 + lm;
        int kp = kcl ^ ((r >> 2) & 3);
        af[mt] = *(const short8*)(As[cur] + r * 32 + kp * 8);
      }
#pragma unroll
      for (int nt = 0; nt < 4; ++nt) {
        int r = wn + nt * 16 + lm;
        int kp = kcl ^ ((r >> 2) & 3);
        bfr[nt] = *(const short8*)(Bs[cur] + r * 32 + kp * 8);
      }
#pragma unroll
      for (int mt = 0; mt < 4; ++mt)
#pragma unroll
        for (int nt = 0; nt < 4; ++nt)
          acc[mt][nt] = __builtin_amdgcn_mfma_f32_16x16x32_bf16(af[mt], bfr[nt], acc[mt][nt], 0, 0, 0);
    }
    if (BNFUSE && nk < K)      // BN+write after compute: MFMA hid the raw-load latency
      procA(cur ^ 1, nk, raw);
    __syncthreads();           // drains vmcnt+lgkmcnt: next buffer ready, reads done
    cur ^= 1;
  }
  // epilogue: store C (C/D layout col=lane&15, row=(lane>>4)*4+reg) + column stats
  int lm = lane & 15, lq = lane >> 4;
  float bv[4];
#pragma unroll
  for (int nt = 0; nt < 4; ++nt) bv[nt] = bias[bn + wn + nt * 16 + lm];
  float ps[4] = {}, pq[4] = {};
  if (!TRANSP) {
#pragma unroll
    for (int mt = 0; mt < 4; ++mt)
#pragma unroll
      for (int r4 = 0; r4 < 4; ++r4) {
        int rowg = bm + wm + mt * 16 + lq * 4 + r4;
        unsigned short* cp = C + (size_t)rowg * Nc + bn + wn + lm;
#pragma unroll
        for (int nt = 0; nt < 4; ++nt) {
          unsigned short us = f2bf(acc[mt][nt][r4] + bv[nt]);
          cp[nt * 16] = us;
          float vr = bf2f(us);           // stats on the bf16-rounded stored value
          ps[nt] += vr; pq[nt] += vr * vr;
        }
      }
  } else {
    int bq = bm >> 13;                   // batch (bm multiple of 128, 8192%128==0)
    int nbase = (bm & (NN - 1)) + wm + lq * 4;
#pragma unroll
    for (int mt = 0; mt < 4; ++mt) {
      int nn = nbase + mt * 16;
#pragma unroll
      for (int nt = 0; nt < 4; ++nt) {
        int ch = wn + nt * 16 + lm;      // bn == 0 for CH2=128
        shortx4 pk;
#pragma unroll
        for (int r4 = 0; r4 < 4; ++r4) {
          unsigned short us = f2bf(acc[mt][nt][r4] + bv[nt]);
          pk[r4] = (short)us;
          float vr = bf2f(us);
          ps[nt] += vr; pq[nt] += vr * vr;
        }
        *(shortx4*)(C + (((size_t)(bq * CH2 + ch)) << 13) + nn) = pk;
      }
    }
  }
  float* colsum = (float*)As;          // reuse LDS (all waves past last barrier)
  float* colsq  = colsum + 128;
  if (tid < 128) { colsum[tid] = 0.f; colsq[tid] = 0.f; }
  __syncthreads();
#pragma unroll
  for (int nt = 0; nt < 4; ++nt) {
    float s = ps[nt], q = pq[nt];
    s += __shfl_down(s, 32); s += __shfl_down(s, 16);
    q += __shfl_down(q, 32); q += __shfl_down(q, 16);
    if (lq == 0) {
      atomicAdd(&colsum[wn + nt * 16 + lm], s);
      atomicAdd(&colsq [wn + nt * 16 + lm], q);
    }
  }
  __syncthreads();
  if (tid < 128) {
    atomicAdd(&osum[bn + tid], colsum[tid]);
    atomicAdd(&osq [bn + tid], colsq[tid]);
  }
}

// ---------- elementwise BN+ReLU + fp32 convert: zT [B][128][N] bf16 -> out fp32 ----------
__global__ __launch_bounds__(256) void out_cvt(const unsigned short* __restrict__ zT,
                                               const float* __restrict__ sum1, const float* __restrict__ sq1,
                                               const float* __restrict__ s1, const float* __restrict__ bb1,
                                               float* __restrict__ out) {
  size_t gid = (size_t)blockIdx.x * 256 + threadIdx.x;
  size_t base = gid * 8;                       // 8 elems/thread, one n-row segment
  int ch = (int)((base >> 13) & (CH2 - 1));
  const float invR = 1.0f / RTOT;
  float mu = sum1[ch] * invR;
  float var = sq1[ch] * invR - mu * mu;
  float a = s1[ch] * (1.0f / sqrtf(var + 1e-5f));
  float c = bb1[ch] - mu * a;
  short8 z = *(const short8*)(zT + base);
  floatx4 o0, o1;
#pragma unroll
  for (int j = 0; j < 4; ++j) o0[j] = fmaxf(fmaf(bf2f((unsigned short)z[j]), a, c), 0.f);
#pragma unroll
  for (int j = 0; j < 4; ++j) o1[j] = fmaxf(fmaf(bf2f((unsigned short)z[j + 4]), a, c), 0.f);
  *(floatx4*)(out + base) = o0;
  *(floatx4*)(out + base + 4) = o1;
}

extern "C" void kernel_launch(void* const* d_in, const int* in_sizes, int n_in,
                              void* d_out, int out_size, void* d_ws, size_t ws_size,
                              hipStream_t stream) {
  const float* xyz1    = (const float*)d_in[0];
  const float* xyz2    = (const float*)d_in[1];
  const float* points1 = (const float*)d_in[2];
  const float* points2 = (const float*)d_in[3];
  const float* w0  = (const float*)d_in[4];
  const float* cb0 = (const float*)d_in[5];
  const float* s0  = (const float*)d_in[6];
  const float* bb0 = (const float*)d_in[7];
  const float* w1  = (const float*)d_in[8];
  const float* cb1 = (const float*)d_in[9];
  const float* s1  = (const float*)d_in[10];
  const float* bb1 = (const float*)d_in[11];

  float* ws = (float*)d_ws;
  // layout (float units; all 16B-aligned)
  float*          p2t  = ws;                               // 2,097,152
  unsigned short* Z0   = (unsigned short*)(ws + 8388608);  // R*256 bf16
  unsigned short* zT   = (unsigned short*)(ws + 16777216); // R*128 bf16, [B][128][N]
  unsigned short* w0T  = (unsigned short*)(ws + 20971520); //    24,576
  unsigned short* w1T  = (unsigned short*)(ws + 20996096); //    16,384
  float*          stats= ws + 21012480;                    //       768

  float* sum0 = stats;        float* sq0 = stats + 256;
  float* sum1 = stats + 512;  float* sq1 = stats + 640;

  // 1: transposes + weight cvt + stats zero (all independent)
  prep<<<2129, 256, 0, stream>>>(points2, p2t, w0, w0T, w1, w1T, stats);

  // 2: 3-NN + interp + GEMM0 + BN0 stats (fully fused, sync-free)
  knn3_g0<<<RTOT / 64, 512, 0, stream>>>(xyz1, xyz2, points1, p2t,
                                         w0T, cb0, sum0, sq0, Z0);

  // 3: zT = (relu(BN0(Z0)) @ W1 + b1)^T  (BN coeffs in prologue), + sums for BN1
  gemm_mfma<1, CH1, 1><<<dim3(CH2 / 128, RTOT / 128), 256, 0, stream>>>(
      Z0, w1T, cb1, sum0, sq0, s0, bb0, sum1, sq1, zT, CH2);

  // 4: out = relu(BN1(zT)) as fp32, pure elementwise
  out_cvt<<<RTOT * CH2 / 8 / 256, 256, 0, stream>>>(
      zT, sum1, sq1, s1, bb1, (float*)d_out);
}

// Round 11
// 198.152 us; speedup vs baseline: 4.1133x; 1.0594x over previous
//
#include <hip/hip_runtime.h>

#define BB 8
#define NN 8192
#define SS 2048
#define DD1 64
#define DD2 128
#define CIN 192
#define CH1 256
#define CH2 128
#define RTOT (BB*NN)   // 65536
#define KCHUNK 256
#define NCHK 8

typedef __attribute__((ext_vector_type(8))) short short8;
typedef __attribute__((ext_vector_type(4))) short shortx4;
typedef __attribute__((ext_vector_type(4))) float floatx4;
typedef __attribute__((ext_vector_type(4))) unsigned uintx4;

__device__ __forceinline__ unsigned short f2bf(float f) {
  unsigned u = __float_as_uint(f);
  u += 0x7fff + ((u >> 16) & 1);   // round-to-nearest-even
  return (unsigned short)(u >> 16);
}
__device__ __forceinline__ float bf2f(unsigned short h) {
  return __uint_as_float(((unsigned)h) << 16);
}

// ---------- fused prep: p2t transpose (2048 blks) + w0T (48) + w1T (32) + stats zero (1) ----------
__global__ __launch_bounds__(256) void prep(const float* __restrict__ points2, float* __restrict__ p2t,
                                            const float* __restrict__ w0, unsigned short* __restrict__ w0T,
                                            const float* __restrict__ w1, unsigned short* __restrict__ w1T,
                                            float* __restrict__ stats) {
  __shared__ float tile[32][33];
  int blk = blockIdx.x, tid = threadIdx.x;
  int tx = tid & 31, ty = tid >> 5;
  if (blk < 2048) {          // points2 [B][128][S] -> p2t [B][S][128]
    int z = blk >> 8, rem = blk & 255;
    int gy = rem >> 6, gx = rem & 63;
    const float* src = points2 + (size_t)z * DD2 * SS;
    float* dst = p2t + (size_t)z * DD2 * SS;
    int c0 = gx * 32, r0 = gy * 32;
    for (int i = ty; i < 32; i += 8)
      tile[i][tx] = src[(size_t)(r0 + i) * SS + (c0 + tx)];
    __syncthreads();
    for (int i = ty; i < 32; i += 8)
      dst[(size_t)(c0 + i) * DD2 + (r0 + tx)] = tile[tx][i];
  } else if (blk < 2096) {   // w0 [192][256] -> w0T [256][192] bf16
    int r = blk - 2048;
    int gy = r >> 3, gx = r & 7;
    int c0 = gx * 32, r0 = gy * 32;
    for (int i = ty; i < 32; i += 8)
      tile[i][tx] = w0[(size_t)(r0 + i) * CH1 + (c0 + tx)];
    __syncthreads();
    for (int i = ty; i < 32; i += 8)
      w0T[(size_t)(c0 + i) * CIN + (r0 + tx)] = f2bf(tile[tx][i]);
  } else if (blk < 2128) {   // w1 [256][128] -> w1T [128][256] bf16
    int r = blk - 2096;
    int gy = r >> 2, gx = r & 3;
    int c0 = gx * 32, r0 = gy * 32;
    for (int i = ty; i < 32; i += 8)
      tile[i][tx] = w1[(size_t)(r0 + i) * CH2 + (c0 + tx)];
    __syncthreads();
    for (int i = ty; i < 32; i += 8)
      w1T[(size_t)(c0 + i) * CH1 + (r0 + tx)] = f2bf(tile[tx][i]);
  } else {
    for (int i = tid; i < 768; i += 256) stats[i] = 0.f;
  }
}

// ---------- fused 3-NN + interp + GEMM0 (+BN0 stats): one block = 64 rows, sync-free ----------
// r10 lesson: Bs staging (16KB) pushed LDS to 57KB -> 2 blocks/CU -> scan lost half its
// occupancy (+27us). Fix: NO B-tile staging. w0T (98KB) is L2-resident across all 1024
// blocks; phase F loads B-fragments directly global->VGPR. Verified value-identical:
// the old stage(XOR-swizzle)+read(XOR-swizzle) round-trip returns exactly
// w0T[r][k0+kcl*8..+8]. Benefits: LDS = 40960B exactly -> 4 blocks/CU (proven r5
// config); phase F is BARRIER-FREE after the H-publish sync (waves drain
// independently); Bs LDS traffic gone. launch_bounds(512,8) caps VGPR at 64.
__global__ __launch_bounds__(512, 8) void knn3_g0(const float* __restrict__ xyz1,
                                                  const float* __restrict__ xyz2,
                                                  const float* __restrict__ points1,
                                                  const float* __restrict__ p2t,
                                                  const unsigned short* __restrict__ w0T,
                                                  const float* __restrict__ cb0,
                                                  float* __restrict__ osum, float* __restrict__ osq,
                                                  unsigned short* __restrict__ Z0) {
  __shared__ __align__(16) union LU {
    float coords[4][SS];           // 32 KB: x,y,z,|x|^2 — phases A-C
    unsigned short H[64][200];     // 25.6 KB: H rows (192 cols + 8 pad) — phases D-F
  } u;
  __shared__ __align__(16) unsigned ck[NCHK][64][4];   // 8 KB; tail reused post-rescore
  int* ldsI   = (int*)&ck[0][0][0];          // [64][3] — aliases ck, written after barrier
  float* ldsW = (float*)&ck[0][0][0] + 192;  // [64][3]
  int tid = threadIdx.x;
  int r0 = blockIdx.x * 64;
  int b = r0 >> 13;                 // N = 8192
  int n0 = r0 & (NN - 1);
  const float* x2 = xyz2 + (size_t)b * 3 * SS;
  for (int i = tid; i < SS; i += 512) {
    float xv = x2[i], yv = x2[SS + i], zv = x2[2 * SS + i];
    u.coords[0][i] = xv;
    u.coords[1][i] = yv;
    u.coords[2][i] = zv;
    u.coords[3][i] = xv * xv + yv * yv + zv * zv;
  }
  __syncthreads();
  int row = tid & 63, chk = tid >> 6;   // chunk wave-uniform -> LDS broadcasts
  int n = n0 + row;
  const float* x1 = xyz1 + (size_t)b * 3 * NN;
  float px = x1[n], py = x1[NN + n], pz = x1[2 * NN + n];
  float qx = -2.f * px, qy = -2.f * py, qz = -2.f * pz;
  float pp = px * px + py * py + pz * pz;
  floatx4 qx4 = {qx, qx, qx, qx}, qy4 = {qy, qy, qy, qy};
  floatx4 qz4 = {qz, qz, qz, qz}, pp4 = {pp, pp, pp, pp};
  unsigned c0 = 0xFFFFFFFFu, c1 = 0xFFFFFFFFu, c2 = 0xFFFFFFFFu, c3 = 0xFFFFFFFFu;
  int sbeg = (int)__builtin_amdgcn_readfirstlane((unsigned)(chk * KCHUNK));
#pragma unroll 2
  for (int s8 = sbeg; s8 < sbeg + KCHUNK; s8 += 8) {
#pragma unroll
    for (int p = 0; p < 2; ++p) {
      floatx4 xv = *(const floatx4*)&u.coords[0][s8 + 4 * p];
      floatx4 yv = *(const floatx4*)&u.coords[1][s8 + 4 * p];
      floatx4 zv = *(const floatx4*)&u.coords[2][s8 + 4 * p];
      floatx4 wv = *(const floatx4*)&u.coords[3][s8 + 4 * p];
      floatx4 d = xv * qx4 + wv;        // fma
      d = yv * qy4 + d;                 // fma
      d = zv * qz4 + d;                 // fma
      d = d + pp4;                      // add; d >= 0 (exact-ish |p-x|^2)
#pragma unroll
      for (int e = 0; e < 4; ++e) {
        unsigned k = (__float_as_uint(d[e]) & 0xFFFFF800u) | (unsigned)(s8 + 4 * p + e);
        // sorted top-4 insert via order statistics: new ci = med3(c[i-1], ci, k)
        unsigned m1, m2, m3;
        asm("v_med3_u32 %0, %1, %2, %3" : "=v"(m1) : "v"(c0), "v"(c1), "v"(k));
        asm("v_med3_u32 %0, %1, %2, %3" : "=v"(m2) : "v"(c1), "v"(c2), "v"(k));
        asm("v_med3_u32 %0, %1, %2, %3" : "=v"(m3) : "v"(c2), "v"(c3), "v"(k));
        c0 = __builtin_elementwise_min(c0, k);   // v_min_u32
        c1 = m1; c2 = m2; c3 = m3;
      }
    }
  }
  *(uintx4*)&ck[chk][row][0] = (uintx4){c0, c1, c2, c3};
  // prefetch the p1 tile into registers: latency hides under the rescore
  floatx4 pv[2];
  const float* p1 = points1 + (size_t)b * DD1 * NN;
#pragma unroll
  for (int t = 0; t < 2; ++t) {
    int i = tid + t * 512;             // 0..1023 = 64ch x 16 float4
    int ch = i >> 4, q = i & 15;
    pv[t] = *(const floatx4*)(p1 + (size_t)ch * NN + n0 + q * 4);
  }
  __syncthreads();
  // rescore into registers (reads u.coords + ck; no LDS writes yet)
  int j0, j1, j2; float fw0, fw1, fw2;
  if (tid < 64) {
    float qpx = x1[n0 + tid], qpy = x1[NN + n0 + tid], qpz = x1[2 * NN + n0 + tid];
    double e0 = 1e300, e1 = 1e300, e2 = 1e300;
    j0 = 0x7fffffff; j1 = 0x7fffffff; j2 = 0x7fffffff;
#pragma unroll
    for (int c = 0; c < NCHK; ++c)
#pragma unroll
      for (int t = 0; t < 4; ++t) {
        int si = (int)(ck[c][tid][t] & 0x7FFu);
        double dx = (double)u.coords[0][si] - (double)qpx;
        double dy = (double)u.coords[1][si] - (double)qpy;
        double dz = (double)u.coords[2][si] - (double)qpz;
        double d = dx * dx + dy * dy + dz * dz;
        if (d < e2 || (d == e2 && si < j2)) {
          if (d < e1 || (d == e1 && si < j1)) {
            e2 = e1; j2 = j1;
            if (d < e0 || (d == e0 && si < j0)) { e1 = e0; j1 = j0; e0 = d; j0 = si; }
            else                                { e1 = d;  j1 = si; }
          } else { e2 = d; j2 = si; }
        }
      }
    double rr0 = 1.0 / (e0 + 1e-8), rr1 = 1.0 / (e1 + 1e-8), rr2 = 1.0 / (e2 + 1e-8);
    double sw = rr0 + rr1 + rr2;
    fw0 = (float)(rr0 / sw); fw1 = (float)(rr1 / sw); fw2 = (float)(rr2 / sw);
  }
  __syncthreads();                      // all ck/coords reads done; union region writable
  // phase D': H[:,0:64] = f2bf(p1^T)  (same f2bf values as the old H0 columns)
#pragma unroll
  for (int t = 0; t < 2; ++t) {
    int i = tid + t * 512;
    int ch = i >> 4, q = i & 15;
#pragma unroll
    for (int e = 0; e < 4; ++e)
      u.H[q * 4 + e][ch] = f2bf(pv[t][e]);
  }
  if (tid < 64) {                       // ldsI/ldsW into ck's (consumed) region
    ldsI[tid * 3 + 0] = j0; ldsI[tid * 3 + 1] = j1; ldsI[tid * 3 + 2] = j2;
    ldsW[tid * 3 + 0] = fw0; ldsW[tid * 3 + 1] = fw1; ldsW[tid * 3 + 2] = fw2;
  }
  __syncthreads();
  // phase E': interp -> H[:,64:192]
  const float* base = p2t + (size_t)b * SS * DD2;
  for (int i = tid; i < 64 * 32; i += 512) {   // 32 interp quad-cols per row
    int rr = i >> 5;
    int cc = (i & 31) * 4;
    floatx4 g0 = *(const floatx4*)(base + (size_t)ldsI[rr * 3 + 0] * DD2 + cc);
    floatx4 g1 = *(const floatx4*)(base + (size_t)ldsI[rr * 3 + 1] * DD2 + cc);
    floatx4 g2 = *(const floatx4*)(base + (size_t)ldsI[rr * 3 + 2] * DD2 + cc);
    float w0 = ldsW[rr * 3 + 0], w1 = ldsW[rr * 3 + 1], w2 = ldsW[rr * 3 + 2];
    shortx4 pk;
#pragma unroll
    for (int e = 0; e < 4; ++e)
      pk[e] = (short)f2bf(w0 * g0[e] + w1 * g1[e] + w2 * g2[e]);
    *(shortx4*)&u.H[rr][DD1 + cc] = pk;
  }
  __syncthreads();                      // H published — phase F needs no further barriers
  // phase F: Z0[r0..r0+63][0..255] = H @ w0T^T + cb0, + BN0 column stats.
  // B-fragments straight from global (L2-resident w0T), A from LDS H.
  int lane = tid & 63, w = tid >> 6;
  int wn = w << 5;                       // 32 output cols per wave (8 waves x 32 = 256)
  int kcl = lane >> 4, lm = lane & 15, lq = lane >> 4;
  floatx4 acc[4][2] = {};                // [mt][nt]: 4 m-frags x 2 n-frags
#pragma unroll
  for (int k0 = 0; k0 < CIN; k0 += 32) {
    short8 af[4], bfr[2];
#pragma unroll
    for (int nt = 0; nt < 2; ++nt)       // direct global load: w0T[r][k0+kcl*8..+8]
      bfr[nt] = *(const short8*)(w0T + (size_t)(wn + nt * 16 + lm) * CIN + k0 + kcl * 8);
#pragma unroll
    for (int mt = 0; mt < 4; ++mt)       // A from H (plain layout)
      af[mt] = *(const short8*)&u.H[mt * 16 + lm][k0 + kcl * 8];
#pragma unroll
    for (int mt = 0; mt < 4; ++mt)
#pragma unroll
      for (int nt = 0; nt < 2; ++nt)
        acc[mt][nt] = __builtin_amdgcn_mfma_f32_16x16x32_bf16(af[mt], bfr[nt], acc[mt][nt], 0, 0, 0);
  }
  // epilogue: Z0 store (C/D layout col=lane&15, row=(lane>>4)*4+reg) + column stats
  float bv[2];
#pragma unroll
  for (int nt = 0; nt < 2; ++nt) bv[nt] = cb0[wn + nt * 16 + lm];
  float ps[2] = {}, pq[2] = {};
#pragma unroll
  for (int mt = 0; mt < 4; ++mt)
#pragma unroll
    for (int r4 = 0; r4 < 4; ++r4) {
      int rowg = r0 + mt * 16 + lq * 4 + r4;
      unsigned short* cp = Z0 + (size_t)rowg * CH1 + wn + lm;
#pragma unroll
      for (int nt = 0; nt < 2; ++nt) {
        unsigned short us = f2bf(acc[mt][nt][r4] + bv[nt]);
        cp[nt * 16] = us;
        float vr = bf2f(us);             // stats on the bf16-rounded stored value
        ps[nt] += vr; pq[nt] += vr * vr;
      }
    }
#pragma unroll
  for (int nt = 0; nt < 2; ++nt) {       // waves own disjoint cols -> direct global adds
    float s = ps[nt], q = pq[nt];
    s += __shfl_down(s, 32); s += __shfl_down(s, 16);
    q += __shfl_down(q, 32); q += __shfl_down(q, 16);
    if (lq == 0) {
      atomicAdd(&osum[wn + nt * 16 + lm], s);
      atomicAdd(&osq [wn + nt * 16 + lm], q);
    }
  }
}

// ---------- bf16 MFMA GEMM + fused column stats — only BNFUSE=1 TRANSP=1 used now ----------
template<int BNFUSE, int K, int TRANSP>
__global__ __launch_bounds__(256) void gemm_mfma(
    const unsigned short* __restrict__ A,
    const unsigned short* __restrict__ BT,
    const float* __restrict__ bias,
    const float* __restrict__ psum, const float* __restrict__ psq,
    const float* __restrict__ pscale, const float* __restrict__ pbias,
    float* __restrict__ osum, float* __restrict__ osq,
    unsigned short* __restrict__ C, int Nc)
{
  __shared__ __align__(16) unsigned short As[2][128 * 32];
  __shared__ __align__(16) unsigned short Bs[2][128 * 32];
  __shared__ float sa[BNFUSE ? 256 : 1];
  __shared__ float sc[BNFUSE ? 256 : 1];
  int tid = threadIdx.x;
  int lane = tid & 63, w = tid >> 6;
  int bn = blockIdx.x << 7, bm = blockIdx.y << 7;
  int wm = (w & 1) << 6, wn = (w >> 1) << 6;
  if (BNFUSE) {
    const float invR = 1.0f / RTOT;
    for (int i = tid; i < K; i += 256) {
      float mu = psum[i] * invR;
      float var = psq[i] * invR - mu * mu;
      float aa = pscale[i] * (1.0f / sqrtf(var + 1e-5f));
      sa[i] = aa; sc[i] = pbias[i] - mu * aa;
    }
    __syncthreads();
  }
  floatx4 acc[4][4] = {};   // [mt][nt]

  auto stageB = [&](int buf, int k0) {
#pragma unroll
    for (int t = 0; t < 2; ++t) {
      int s = (w * 2 + t) * 64 + lane;
      int r = s >> 2;
      int kc = (s & 3) ^ ((r >> 2) & 3);
      const unsigned short* gp = BT + (size_t)(bn + r) * K + (k0 + kc * 8);
      __builtin_amdgcn_global_load_lds(
          (const __attribute__((address_space(1))) void*)gp,
          (__attribute__((address_space(3))) void*)(Bs[buf] + (w * 2 + t) * 512),
          16, 0, 0);
    }
  };
  auto stageA_lds = [&](int buf, int k0) {
#pragma unroll
    for (int t = 0; t < 2; ++t) {
      int s = (w * 2 + t) * 64 + lane;
      int r = s >> 2;
      int kc = (s & 3) ^ ((r >> 2) & 3);
      const unsigned short* gp = A + (size_t)(bm + r) * K + (k0 + kc * 8);
      __builtin_amdgcn_global_load_lds(
          (const __attribute__((address_space(1))) void*)gp,
          (__attribute__((address_space(3))) void*)(As[buf] + (w * 2 + t) * 512),
          16, 0, 0);
    }
  };
  auto procA = [&](int buf, int k0, short8* raw) {
#pragma unroll
    for (int t = 0; t < 2; ++t) {
      int s = t * 256 + tid;
      int r = s >> 2;
      int kc = (s & 3) ^ ((r >> 2) & 3);
      int kg = k0 + kc * 8;
      short8 ov;
#pragma unroll
      for (int j = 0; j < 8; ++j) {
        float v = bf2f((unsigned short)raw[t][j]);
        v = fmaxf(fmaf(v, sa[kg + j], sc[kg + j]), 0.f);
        ov[j] = (short)f2bf(v);
      }
      *(short8*)(As[buf] + s * 8) = ov;
    }
  };

  // prologue: fill buffer 0
  if (!BNFUSE) {
    stageA_lds(0, 0);
  } else {
    short8 raw[2];
#pragma unroll
    for (int t = 0; t < 2; ++t) {
      int s = t * 256 + tid;
      int r = s >> 2;
      int kc = (s & 3) ^ ((r >> 2) & 3);
      raw[t] = *(const short8*)(A + (size_t)(bm + r) * K + (kc * 8));
    }
    procA(0, 0, raw);
  }
  stageB(0, 0);
  __syncthreads();

  int cur = 0;
  for (int k0 = 0; k0 < K; k0 += 32) {
    int nk = k0 + 32;
    short8 raw[2];
    if (nk < K) {              // issue next tile's loads before computing current
      if (!BNFUSE) {
        stageA_lds(cur ^ 1, nk);
      } else {
#pragma unroll
        for (int t = 0; t < 2; ++t) {
          int s = t * 256 + tid;
          int r = s >> 2;
          int kc = (s & 3) ^ ((r >> 2) & 3);
          raw[t] = *(const short8*)(A + (size_t)(bm + r) * K + (nk + kc * 8));
        }
      }
      stageB(cur ^ 1, nk);
    }
    // compute current buffer
    {
      short8 af[4], bfr[4];
      int kcl = lane >> 4;
      int lm = lane & 15;
#pragma unroll
      for (int mt = 0; mt < 4; ++mt) {
        int r = wm + mt * 16 + lm;
        int kp = kcl ^ ((r >> 2) & 3);
        af[mt] = *(const short8*)(As[cur] + r * 32 + kp * 8);
      }
#pragma unroll
      for (int nt = 0; nt < 4; ++nt) {
        int r = wn + nt * 16 + lm;
        int kp = kcl ^ ((r >> 2) & 3);
        bfr[nt] = *(const short8*)(Bs[cur] + r * 32 + kp * 8);
      }
#pragma unroll
      for (int mt = 0; mt < 4; ++mt)
#pragma unroll
        for (int nt = 0; nt < 4; ++nt)
          acc[mt][nt] = __builtin_amdgcn_mfma_f32_16x16x32_bf16(af[mt], bfr[nt], acc[mt][nt], 0, 0, 0);
    }
    if (BNFUSE && nk < K)      // BN+write after compute: MFMA hid the raw-load latency
      procA(cur ^ 1, nk, raw);
    __syncthreads();           // drains vmcnt+lgkmcnt: next buffer ready, reads done
    cur ^= 1;
  }
  // epilogue: store C (C/D layout col=lane&15, row=(lane>>4)*4+reg) + column stats
  int lm = lane & 15, lq = lane >> 4;
  float bv[4];
#pragma unroll
  for (int nt = 0; nt < 4; ++nt) bv[nt] = bias[bn + wn + nt * 16 + lm];
  float ps[4] = {}, pq[4] = {};
  if (!TRANSP) {
#pragma unroll
    for (int mt = 0; mt < 4; ++mt)
#pragma unroll
      for (int r4 = 0; r4 < 4; ++r4) {
        int rowg = bm + wm + mt * 16 + lq * 4 + r4;
        unsigned short* cp = C + (size_t)rowg * Nc + bn + wn + lm;
#pragma unroll
        for (int nt = 0; nt < 4; ++nt) {
          unsigned short us = f2bf(acc[mt][nt][r4] + bv[nt]);
          cp[nt * 16] = us;
          float vr = bf2f(us);           // stats on the bf16-rounded stored value
          ps[nt] += vr; pq[nt] += vr * vr;
        }
      }
  } else {
    int bq = bm >> 13;                   // batch (bm multiple of 128, 8192%128==0)
    int nbase = (bm & (NN - 1)) + wm + lq * 4;
#pragma unroll
    for (int mt = 0; mt < 4; ++mt) {
      int nn = nbase + mt * 16;
#pragma unroll
      for (int nt = 0; nt < 4; ++nt) {
        int ch = wn + nt * 16 + lm;      // bn == 0 for CH2=128
        shortx4 pk;
#pragma unroll
        for (int r4 = 0; r4 < 4; ++r4) {
          unsigned short us = f2bf(acc[mt][nt][r4] + bv[nt]);
          pk[r4] = (short)us;
          float vr = bf2f(us);
          ps[nt] += vr; pq[nt] += vr * vr;
        }
        *(shortx4*)(C + (((size_t)(bq * CH2 + ch)) << 13) + nn) = pk;
      }
    }
  }
  float* colsum = (float*)As;          // reuse LDS (all waves past last barrier)
  float* colsq  = colsum + 128;
  if (tid < 128) { colsum[tid] = 0.f; colsq[tid] = 0.f; }
  __syncthreads();
#pragma unroll
  for (int nt = 0; nt < 4; ++nt) {
    float s = ps[nt], q = pq[nt];
    s += __shfl_down(s, 32); s += __shfl_down(s, 16);
    q += __shfl_down(q, 32); q += __shfl_down(q, 16);
    if (lq == 0) {
      atomicAdd(&colsum[wn + nt * 16 + lm], s);
      atomicAdd(&colsq [wn + nt * 16 + lm], q);
    }
  }
  __syncthreads();
  if (tid < 128) {
    atomicAdd(&osum[bn + tid], colsum[tid]);
    atomicAdd(&osq [bn + tid], colsq[tid]);
  }
}

// ---------- elementwise BN+ReLU + fp32 convert: zT [B][128][N] bf16 -> out fp32 ----------
__global__ __launch_bounds__(256) void out_cvt(const unsigned short* __restrict__ zT,
                                               const float* __restrict__ sum1, const float* __restrict__ sq1,
                                               const float* __restrict__ s1, const float* __restrict__ bb1,
                                               float* __restrict__ out) {
  size_t gid = (size_t)blockIdx.x * 256 + threadIdx.x;
  size_t base = gid * 8;                       // 8 elems/thread, one n-row segment
  int ch = (int)((base >> 13) & (CH2 - 1));
  const float invR = 1.0f / RTOT;
  float mu = sum1[ch] * invR;
  float var = sq1[ch] * invR - mu * mu;
  float a = s1[ch] * (1.0f / sqrtf(var + 1e-5f));
  float c = bb1[ch] - mu * a;
  short8 z = *(const short8*)(zT + base);
  floatx4 o0, o1;
#pragma unroll
  for (int j = 0; j < 4; ++j) o0[j] = fmaxf(fmaf(bf2f((unsigned short)z[j]), a, c), 0.f);
#pragma unroll
  for (int j = 0; j < 4; ++j) o1[j] = fmaxf(fmaf(bf2f((unsigned short)z[j + 4]), a, c), 0.f);
  *(floatx4*)(out + base) = o0;
  *(floatx4*)(out + base + 4) = o1;
}

extern "C" void kernel_launch(void* const* d_in, const int* in_sizes, int n_in,
                              void* d_out, int out_size, void* d_ws, size_t ws_size,
                              hipStream_t stream) {
  const float* xyz1    = (const float*)d_in[0];
  const float* xyz2    = (const float*)d_in[1];
  const float* points1 = (const float*)d_in[2];
  const float* points2 = (const float*)d_in[3];
  const float* w0  = (const float*)d_in[4];
  const float* cb0 = (const float*)d_in[5];
  const float* s0  = (const float*)d_in[6];
  const float* bb0 = (const float*)d_in[7];
  const float* w1  = (const float*)d_in[8];
  const float* cb1 = (const float*)d_in[9];
  const float* s1  = (const float*)d_in[10];
  const float* bb1 = (const float*)d_in[11];

  float* ws = (float*)d_ws;
  // layout (float units; all 16B-aligned)
  float*          p2t  = ws;                               // 2,097,152
  unsigned short* Z0   = (unsigned short*)(ws + 8388608);  // R*256 bf16
  unsigned short* zT   = (unsigned short*)(ws + 16777216); // R*128 bf16, [B][128][N]
  unsigned short* w0T  = (unsigned short*)(ws + 20971520); //    24,576
  unsigned short* w1T  = (unsigned short*)(ws + 20996096); //    16,384
  float*          stats= ws + 21012480;                    //       768

  float* sum0 = stats;        float* sq0 = stats + 256;
  float* sum1 = stats + 512;  float* sq1 = stats + 640;

  // 1: transposes + weight cvt + stats zero (all independent)
  prep<<<2129, 256, 0, stream>>>(points2, p2t, w0, w0T, w1, w1T, stats);

  // 2: 3-NN + interp + GEMM0 + BN0 stats (fully fused, sync-free)
  knn3_g0<<<RTOT / 64, 512, 0, stream>>>(xyz1, xyz2, points1, p2t,
                                         w0T, cb0, sum0, sq0, Z0);

  // 3: zT = (relu(BN0(Z0)) @ W1 + b1)^T  (BN coeffs in prologue), + sums for BN1
  gemm_mfma<1, CH1, 1><<<dim3(CH2 / 128, RTOT / 128), 256, 0, stream>>>(
      Z0, w1T, cb1, sum0, sq0, s0, bb0, sum1, sq1, zT, CH2);

  // 4: out = relu(BN1(zT)) as fp32, pure elementwise
  out_cvt<<<RTOT * CH2 / 8 / 256, 256, 0, stream>>>(
      zT, sum1, sq1, s1, bb1, (float*)d_out);
}

// Round 13
// 193.447 us; speedup vs baseline: 4.2134x; 1.0243x over previous
//
#include <hip/hip_runtime.h>

#define BB 8
#define NN 8192
#define SS 2048
#define DD1 64
#define DD2 128
#define CIN 192
#define CH1 256
#define CH2 128
#define RTOT (BB*NN)   // 65536
#define KCHUNK 256
#define NCHK 8

typedef __attribute__((ext_vector_type(8))) short short8;
typedef __attribute__((ext_vector_type(4))) short shortx4;
typedef __attribute__((ext_vector_type(4))) float floatx4;
typedef __attribute__((ext_vector_type(4))) unsigned uintx4;

__device__ __forceinline__ unsigned short f2bf(float f) {
  unsigned u = __float_as_uint(f);
  u += 0x7fff + ((u >> 16) & 1);   // round-to-nearest-even
  return (unsigned short)(u >> 16);
}
__device__ __forceinline__ float bf2f(unsigned short h) {
  return __uint_as_float(((unsigned)h) << 16);
}

// ---------- fused prep: p2t transpose (2048 blks) + w0T (48) + w1T (32) + stats zero (1) ----------
__global__ __launch_bounds__(256) void prep(const float* __restrict__ points2, float* __restrict__ p2t,
                                            const float* __restrict__ w0, unsigned short* __restrict__ w0T,
                                            const float* __restrict__ w1, unsigned short* __restrict__ w1T,
                                            float* __restrict__ stats) {
  __shared__ float tile[32][33];
  int blk = blockIdx.x, tid = threadIdx.x;
  int tx = tid & 31, ty = tid >> 5;
  if (blk < 2048) {          // points2 [B][128][S] -> p2t [B][S][128]
    int z = blk >> 8, rem = blk & 255;
    int gy = rem >> 6, gx = rem & 63;
    const float* src = points2 + (size_t)z * DD2 * SS;
    float* dst = p2t + (size_t)z * DD2 * SS;
    int c0 = gx * 32, r0 = gy * 32;
    for (int i = ty; i < 32; i += 8)
      tile[i][tx] = src[(size_t)(r0 + i) * SS + (c0 + tx)];
    __syncthreads();
    for (int i = ty; i < 32; i += 8)
      dst[(size_t)(c0 + i) * DD2 + (r0 + tx)] = tile[tx][i];
  } else if (blk < 2096) {   // w0 [192][256] -> w0T [256][192] bf16
    int r = blk - 2048;
    int gy = r >> 3, gx = r & 7;
    int c0 = gx * 32, r0 = gy * 32;
    for (int i = ty; i < 32; i += 8)
      tile[i][tx] = w0[(size_t)(r0 + i) * CH1 + (c0 + tx)];
    __syncthreads();
    for (int i = ty; i < 32; i += 8)
      w0T[(size_t)(c0 + i) * CIN + (r0 + tx)] = f2bf(tile[tx][i]);
  } else if (blk < 2128) {   // w1 [256][128] -> w1T [128][256] bf16
    int r = blk - 2096;
    int gy = r >> 2, gx = r & 3;
    int c0 = gx * 32, r0 = gy * 32;
    for (int i = ty; i < 32; i += 8)
      tile[i][tx] = w1[(size_t)(r0 + i) * CH2 + (c0 + tx)];
    __syncthreads();
    for (int i = ty; i < 32; i += 8)
      w1T[(size_t)(c0 + i) * CH1 + (r0 + tx)] = f2bf(tile[tx][i]);
  } else {
    for (int i = tid; i < 768; i += 256) stats[i] = 0.f;
  }
}

// ---------- fused 3-NN + interp + GEMM0 (+BN0 stats): one block = 64 rows, sync-free ----------
// Scan loop: single base pointer + compile-time stream offsets (8/16/24 KB fit the
// 16-bit DS offset: immediate) -> 1 addr add + 4 ds_read_b128 offset:N per 4-cand
// group; unroll 4 keeps 16 loads in flight. Numerics bit-identical to r11.
__global__ __launch_bounds__(512, 8) void knn3_g0(const float* __restrict__ xyz1,
                                                  const float* __restrict__ xyz2,
                                                  const float* __restrict__ points1,
                                                  const float* __restrict__ p2t,
                                                  const unsigned short* __restrict__ w0T,
                                                  const float* __restrict__ cb0,
                                                  float* __restrict__ osum, float* __restrict__ osq,
                                                  unsigned short* __restrict__ Z0) {
  __shared__ __align__(16) union LU {
    float coords[4][SS];           // 32 KB: x,y,z,|x|^2 — phases A-C
    unsigned short H[64][200];     // 25.6 KB: H rows (192 cols + 8 pad) — phases D-F
  } u;
  __shared__ __align__(16) unsigned ck[NCHK][64][4];   // 8 KB; tail reused post-rescore
  int* ldsI   = (int*)&ck[0][0][0];          // [64][3] — aliases ck, written after barrier
  float* ldsW = (float*)&ck[0][0][0] + 192;  // [64][3]
  int tid = threadIdx.x;
  int r0 = blockIdx.x * 64;
  int b = r0 >> 13;                 // N = 8192
  int n0 = r0 & (NN - 1);
  const float* x2 = xyz2 + (size_t)b * 3 * SS;
  for (int i = tid; i < SS; i += 512) {
    float xv = x2[i], yv = x2[SS + i], zv = x2[2 * SS + i];
    u.coords[0][i] = xv;
    u.coords[1][i] = yv;
    u.coords[2][i] = zv;
    u.coords[3][i] = xv * xv + yv * yv + zv * zv;
  }
  __syncthreads();
  int row = tid & 63, chk = tid >> 6;   // chunk wave-uniform -> LDS broadcasts
  int n = n0 + row;
  const float* x1 = xyz1 + (size_t)b * 3 * NN;
  float px = x1[n], py = x1[NN + n], pz = x1[2 * NN + n];
  float qx = -2.f * px, qy = -2.f * py, qz = -2.f * pz;
  float pp = px * px + py * py + pz * pz;
  floatx4 qx4 = {qx, qx, qx, qx}, qy4 = {qy, qy, qy, qy};
  floatx4 qz4 = {qz, qz, qz, qz}, pp4 = {pp, pp, pp, pp};
  unsigned c0 = 0xFFFFFFFFu, c1 = 0xFFFFFFFFu, c2 = 0xFFFFFFFFu, c3 = 0xFFFFFFFFu;
  int sbeg = (int)__builtin_amdgcn_readfirstlane((unsigned)(chk * KCHUNK));
  const float* cbase = &u.coords[0][0];
  for (int s8 = sbeg; s8 < sbeg + KCHUNK; s8 += 16) {
#pragma unroll
    for (int p = 0; p < 4; ++p) {
      const float* cp = cbase + (s8 + 4 * p);   // one addr; streams via offset: imm
      floatx4 xv = *(const floatx4*)(cp);
      floatx4 yv = *(const floatx4*)(cp + SS);
      floatx4 zv = *(const floatx4*)(cp + 2 * SS);
      floatx4 wv = *(const floatx4*)(cp + 3 * SS);
      floatx4 d = xv * qx4 + wv;        // fma
      d = yv * qy4 + d;                 // fma
      d = zv * qz4 + d;                 // fma
      d = d + pp4;                      // add; d >= 0 (exact-ish |p-x|^2)
#pragma unroll
      for (int e = 0; e < 4; ++e) {
        unsigned k = (__float_as_uint(d[e]) & 0xFFFFF800u) | (unsigned)(s8 + 4 * p + e);
        // sorted top-4 insert via order statistics: new ci = med3(c[i-1], ci, k)
        unsigned m1, m2, m3;
        asm("v_med3_u32 %0, %1, %2, %3" : "=v"(m1) : "v"(c0), "v"(c1), "v"(k));
        asm("v_med3_u32 %0, %1, %2, %3" : "=v"(m2) : "v"(c1), "v"(c2), "v"(k));
        asm("v_med3_u32 %0, %1, %2, %3" : "=v"(m3) : "v"(c2), "v"(c3), "v"(k));
        c0 = __builtin_elementwise_min(c0, k);   // v_min_u32
        c1 = m1; c2 = m2; c3 = m3;
      }
    }
  }
  *(uintx4*)&ck[chk][row][0] = (uintx4){c0, c1, c2, c3};
  // prefetch the p1 tile into registers: latency hides under the rescore
  floatx4 pv[2];
  const float* p1 = points1 + (size_t)b * DD1 * NN;
#pragma unroll
  for (int t = 0; t < 2; ++t) {
    int i = tid + t * 512;             // 0..1023 = 64ch x 16 float4
    int ch = i >> 4, q = i & 15;
    pv[t] = *(const floatx4*)(p1 + (size_t)ch * NN + n0 + q * 4);
  }
  __syncthreads();
  // rescore into registers (reads u.coords + ck; no LDS writes yet)
  int j0, j1, j2; float fw0, fw1, fw2;
  if (tid < 64) {
    float qpx = x1[n0 + tid], qpy = x1[NN + n0 + tid], qpz = x1[2 * NN + n0 + tid];
    double e0 = 1e300, e1 = 1e300, e2 = 1e300;
    j0 = 0x7fffffff; j1 = 0x7fffffff; j2 = 0x7fffffff;
#pragma unroll
    for (int c = 0; c < NCHK; ++c)
#pragma unroll
      for (int t = 0; t < 4; ++t) {
        int si = (int)(ck[c][tid][t] & 0x7FFu);
        double dx = (double)u.coords[0][si] - (double)qpx;
        double dy = (double)u.coords[1][si] - (double)qpy;
        double dz = (double)u.coords[2][si] - (double)qpz;
        double d = dx * dx + dy * dy + dz * dz;
        if (d < e2 || (d == e2 && si < j2)) {
          if (d < e1 || (d == e1 && si < j1)) {
            e2 = e1; j2 = j1;
            if (d < e0 || (d == e0 && si < j0)) { e1 = e0; j1 = j0; e0 = d; j0 = si; }
            else                                { e1 = d;  j1 = si; }
          } else { e2 = d; j2 = si; }
        }
      }
    double rr0 = 1.0 / (e0 + 1e-8), rr1 = 1.0 / (e1 + 1e-8), rr2 = 1.0 / (e2 + 1e-8);
    double sw = rr0 + rr1 + rr2;
    fw0 = (float)(rr0 / sw); fw1 = (float)(rr1 / sw); fw2 = (float)(rr2 / sw);
  }
  __syncthreads();                      // all ck/coords reads done; union region writable
  // phase D': H[:,0:64] = f2bf(p1^T)  (same f2bf values as the old H0 columns)
#pragma unroll
  for (int t = 0; t < 2; ++t) {
    int i = tid + t * 512;
    int ch = i >> 4, q = i & 15;
#pragma unroll
    for (int e = 0; e < 4; ++e)
      u.H[q * 4 + e][ch] = f2bf(pv[t][e]);
  }
  if (tid < 64) {                       // ldsI/ldsW into ck's (consumed) region
    ldsI[tid * 3 + 0] = j0; ldsI[tid * 3 + 1] = j1; ldsI[tid * 3 + 2] = j2;
    ldsW[tid * 3 + 0] = fw0; ldsW[tid * 3 + 1] = fw1; ldsW[tid * 3 + 2] = fw2;
  }
  __syncthreads();
  // phase E': interp -> H[:,64:192]
  const float* base = p2t + (size_t)b * SS * DD2;
  for (int i = tid; i < 64 * 32; i += 512) {   // 32 interp quad-cols per row
    int rr = i >> 5;
    int cc = (i & 31) * 4;
    floatx4 g0 = *(const floatx4*)(base + (size_t)ldsI[rr * 3 + 0] * DD2 + cc);
    floatx4 g1 = *(const floatx4*)(base + (size_t)ldsI[rr * 3 + 1] * DD2 + cc);
    floatx4 g2 = *(const floatx4*)(base + (size_t)ldsI[rr * 3 + 2] * DD2 + cc);
    float w0 = ldsW[rr * 3 + 0], w1 = ldsW[rr * 3 + 1], w2 = ldsW[rr * 3 + 2];
    shortx4 pk;
#pragma unroll
    for (int e = 0; e < 4; ++e)
      pk[e] = (short)f2bf(w0 * g0[e] + w1 * g1[e] + w2 * g2[e]);
    *(shortx4*)&u.H[rr][DD1 + cc] = pk;
  }
  __syncthreads();                      // H published — phase F needs no further barriers
  // phase F: Z0[r0..r0+63][0..255] = H @ w0T^T + cb0, + BN0 column stats.
  // B-fragments straight from global (L2-resident w0T), A from LDS H.
  int lane = tid & 63, w = tid >> 6;
  int wn = w << 5;                       // 32 output cols per wave (8 waves x 32 = 256)
  int kcl = lane >> 4, lm = lane & 15, lq = lane >> 4;
  floatx4 acc[4][2] = {};                // [mt][nt]: 4 m-frags x 2 n-frags
#pragma unroll
  for (int k0 = 0; k0 < CIN; k0 += 32) {
    short8 af[4], bfr[2];
#pragma unroll
    for (int nt = 0; nt < 2; ++nt)       // direct global load: w0T[r][k0+kcl*8..+8]
      bfr[nt] = *(const short8*)(w0T + (size_t)(wn + nt * 16 + lm) * CIN + k0 + kcl * 8);
#pragma unroll
    for (int mt = 0; mt < 4; ++mt)       // A from H (plain layout)
      af[mt] = *(const short8*)&u.H[mt * 16 + lm][k0 + kcl * 8];
#pragma unroll
    for (int mt = 0; mt < 4; ++mt)
#pragma unroll
      for (int nt = 0; nt < 2; ++nt)
        acc[mt][nt] = __builtin_amdgcn_mfma_f32_16x16x32_bf16(af[mt], bfr[nt], acc[mt][nt], 0, 0, 0);
  }
  // epilogue: Z0 store (C/D layout col=lane&15, row=(lane>>4)*4+reg) + column stats
  float bv[2];
#pragma unroll
  for (int nt = 0; nt < 2; ++nt) bv[nt] = cb0[wn + nt * 16 + lm];
  float ps[2] = {}, pq[2] = {};
#pragma unroll
  for (int mt = 0; mt < 4; ++mt)
#pragma unroll
    for (int r4 = 0; r4 < 4; ++r4) {
      int rowg = r0 + mt * 16 + lq * 4 + r4;
      unsigned short* cp = Z0 + (size_t)rowg * CH1 + wn + lm;
#pragma unroll
      for (int nt = 0; nt < 2; ++nt) {
        unsigned short us = f2bf(acc[mt][nt][r4] + bv[nt]);
        cp[nt * 16] = us;
        float vr = bf2f(us);             // stats on the bf16-rounded stored value
        ps[nt] += vr; pq[nt] += vr * vr;
      }
    }
#pragma unroll
  for (int nt = 0; nt < 2; ++nt) {       // waves own disjoint cols -> direct global adds
    float s = ps[nt], q = pq[nt];
    s += __shfl_down(s, 32); s += __shfl_down(s, 16);
    q += __shfl_down(q, 32); q += __shfl_down(q, 16);
    if (lq == 0) {
      atomicAdd(&osum[wn + nt * 16 + lm], s);
      atomicAdd(&osq [wn + nt * 16 + lm], q);
    }
  }
}

// ---------- bf16 MFMA GEMM + fused column stats — only BNFUSE=1 TRANSP=1 used now ----------
template<int BNFUSE, int K, int TRANSP>
__global__ __launch_bounds__(256) void gemm_mfma(
    const unsigned short* __restrict__ A,
    const unsigned short* __restrict__ BT,
    const float* __restrict__ bias,
    const float* __restrict__ psum, const float* __restrict__ psq,
    const float* __restrict__ pscale, const float* __restrict__ pbias,
    float* __restrict__ osum, float* __restrict__ osq,
    unsigned short* __restrict__ C, int Nc)
{
  __shared__ __align__(16) unsigned short As[2][128 * 32];
  __shared__ __align__(16) unsigned short Bs[2][128 * 32];
  __shared__ float sa[BNFUSE ? 256 : 1];
  __shared__ float sc[BNFUSE ? 256 : 1];
  int tid = threadIdx.x;
  int lane = tid & 63, w = tid >> 6;
  int bn = blockIdx.x << 7, bm = blockIdx.y << 7;
  int wm = (w & 1) << 6, wn = (w >> 1) << 6;
  if (BNFUSE) {
    const float invR = 1.0f / RTOT;
    for (int i = tid; i < K; i += 256) {
      float mu = psum[i] * invR;
      float var = psq[i] * invR - mu * mu;
      float aa = pscale[i] * (1.0f / sqrtf(var + 1e-5f));
      sa[i] = aa; sc[i] = pbias[i] - mu * aa;
    }
    __syncthreads();
  }
  floatx4 acc[4][4] = {};   // [mt][nt]

  auto stageB = [&](int buf, int k0) {
#pragma unroll
    for (int t = 0; t < 2; ++t) {
      int s = (w * 2 + t) * 64 + lane;
      int r = s >> 2;
      int kc = (s & 3) ^ ((r >> 2) & 3);
      const unsigned short* gp = BT + (size_t)(bn + r) * K + (k0 + kc * 8);
      __builtin_amdgcn_global_load_lds(
          (const __attribute__((address_space(1))) void*)gp,
          (__attribute__((address_space(3))) void*)(Bs[buf] + (w * 2 + t) * 512),
          16, 0, 0);
    }
  };
  auto procA = [&](int buf, int k0, short8* raw) {
#pragma unroll
    for (int t = 0; t < 2; ++t) {
      int s = t * 256 + tid;
      int r = s >> 2;
      int kc = (s & 3) ^ ((r >> 2) & 3);
      int kg = k0 + kc * 8;
      short8 ov;
#pragma unroll
      for (int j = 0; j < 8; ++j) {
        float v = bf2f((unsigned short)raw[t][j]);
        v = fmaxf(fmaf(v, sa[kg + j], sc[kg + j]), 0.f);
        ov[j] = (short)f2bf(v);
      }
      *(short8*)(As[buf] + s * 8) = ov;
    }
  };

  // prologue: fill buffer 0
  {
    short8 raw[2];
#pragma unroll
    for (int t = 0; t < 2; ++t) {
      int s = t * 256 + tid;
      int r = s >> 2;
      int kc = (s & 3) ^ ((r >> 2) & 3);
      raw[t] = *(const short8*)(A + (size_t)(bm + r) * K + (kc * 8));
    }
    procA(0, 0, raw);
  }
  stageB(0, 0);
  __syncthreads();

  int cur = 0;
  for (int k0 = 0; k0 < K; k0 += 32) {
    int nk = k0 + 32;
    short8 raw[2];
    if (nk < K) {              // issue next tile's loads before computing current
#pragma unroll
      for (int t = 0; t < 2; ++t) {
        int s = t * 256 + tid;
        int r = s >> 2;
        int kc = (s & 3) ^ ((r >> 2) & 3);
        raw[t] = *(const short8*)(A + (size_t)(bm + r) * K + (nk + kc * 8));
      }
      stageB(cur ^ 1, nk);
    }
    // compute current buffer
    {
      short8 af[4], bfr[4];
      int kcl = lane >> 4;
      int lm = lane & 15;
#pragma unroll
      for (int mt = 0; mt < 4; ++mt) {
        int r = wm + mt * 16 + lm;
        int kp = kcl ^ ((r >> 2) & 3);
        af[mt] = *(const short8*)(As[cur] + r * 32 + kp * 8);
      }
#pragma unroll
      for (int nt = 0; nt < 4; ++nt) {
        int r = wn + nt * 16 + lm;
        int kp = kcl ^ ((r >> 2) & 3);
        bfr[nt] = *(const short8*)(Bs[cur] + r * 32 + kp * 8);
      }
#pragma unroll
      for (int mt = 0; mt < 4; ++mt)
#pragma unroll
        for (int nt = 0; nt < 4; ++nt)
          acc[mt][nt] = __builtin_amdgcn_mfma_f32_16x16x32_bf16(af[mt], bfr[nt], acc[mt][nt], 0, 0, 0);
    }
    if (nk < K)                // BN+write after compute: MFMA hid the raw-load latency
      procA(cur ^ 1, nk, raw);
    __syncthreads();           // drains vmcnt+lgkmcnt: next buffer ready, reads done
    cur ^= 1;
  }
  // epilogue: store C (C/D layout col=lane&15, row=(lane>>4)*4+reg) + column stats
  int lm = lane & 15, lq = lane >> 4;
  float bv[4];
#pragma unroll
  for (int nt = 0; nt < 4; ++nt) bv[nt] = bias[bn + wn + nt * 16 + lm];
  float ps[4] = {}, pq[4] = {};
  {
    int bq = bm >> 13;                   // batch (bm multiple of 128, 8192%128==0)
    int nbase = (bm & (NN - 1)) + wm + lq * 4;
#pragma unroll
    for (int mt = 0; mt < 4; ++mt) {
      int nn = nbase + mt * 16;
#pragma unroll
      for (int nt = 0; nt < 4; ++nt) {
        int ch = wn + nt * 16 + lm;      // bn == 0 for CH2=128
        shortx4 pk;
#pragma unroll
        for (int r4 = 0; r4 < 4; ++r4) {
          unsigned short us = f2bf(acc[mt][nt][r4] + bv[nt]);
          pk[r4] = (short)us;
          float vr = bf2f(us);
          ps[nt] += vr; pq[nt] += vr * vr;
        }
        *(shortx4*)(C + (((size_t)(bq * CH2 + ch)) << 13) + nn) = pk;
      }
    }
  }
  float* colsum = (float*)As;          // reuse LDS (all waves past last barrier)
  float* colsq  = colsum + 128;
  if (tid < 128) { colsum[tid] = 0.f; colsq[tid] = 0.f; }
  __syncthreads();
#pragma unroll
  for (int nt = 0; nt < 4; ++nt) {
    float s = ps[nt], q = pq[nt];
    s += __shfl_down(s, 32); s += __shfl_down(s, 16);
    q += __shfl_down(q, 32); q += __shfl_down(q, 16);
    if (lq == 0) {
      atomicAdd(&colsum[wn + nt * 16 + lm], s);
      atomicAdd(&colsq [wn + nt * 16 + lm], q);
    }
  }
  __syncthreads();
  if (tid < 128) {
    atomicAdd(&osum[bn + tid], colsum[tid]);
    atomicAdd(&osq [bn + tid], colsq[tid]);
  }
}

// ---------- elementwise BN+ReLU + fp32 convert: zT [B][128][N] bf16 -> out fp32 ----------
__global__ __launch_bounds__(256) void out_cvt(const unsigned short* __restrict__ zT,
                                               const float* __restrict__ sum1, const float* __restrict__ sq1,
                                               const float* __restrict__ s1, const float* __restrict__ bb1,
                                               float* __restrict__ out) {
  size_t gid = (size_t)blockIdx.x * 256 + threadIdx.x;
  size_t base = gid * 8;                       // 8 elems/thread, one n-row segment
  int ch = (int)((base >> 13) & (CH2 - 1));
  const float invR = 1.0f / RTOT;
  float mu = sum1[ch] * invR;
  float var = sq1[ch] * invR - mu * mu;
  float a = s1[ch] * (1.0f / sqrtf(var + 1e-5f));
  float c = bb1[ch] - mu * a;
  short8 z = *(const short8*)(zT + base);
  floatx4 o0, o1;
#pragma unroll
  for (int j = 0; j < 4; ++j) o0[j] = fmaxf(fmaf(bf2f((unsigned short)z[j]), a, c), 0.f);
#pragma unroll
  for (int j = 0; j < 4; ++j) o1[j] = fmaxf(fmaf(bf2f((unsigned short)z[j + 4]), a, c), 0.f);
  *(floatx4*)(out + base) = o0;
  *(floatx4*)(out + base + 4) = o1;
}

extern "C" void kernel_launch(void* const* d_in, const int* in_sizes, int n_in,
                              void* d_out, int out_size, void* d_ws, size_t ws_size,
                              hipStream_t stream) {
  const float* xyz1    = (const float*)d_in[0];
  const float* xyz2    = (const float*)d_in[1];
  const float* points1 = (const float*)d_in[2];
  const float* points2 = (const float*)d_in[3];
  const float* w0  = (const float*)d_in[4];
  const float* cb0 = (const float*)d_in[5];
  const float* s0  = (const float*)d_in[6];
  const float* bb0 = (const float*)d_in[7];
  const float* w1  = (const float*)d_in[8];
  const float* cb1 = (const float*)d_in[9];
  const float* s1  = (const float*)d_in[10];
  const float* bb1 = (const float*)d_in[11];

  float* ws = (float*)d_ws;
  // compacted layout, FLOAT units with byte math spelled out (r12 bug: counted
  // shorts as floats -> w1T/stats overlapped w0T/w1T):
  //   p2t   @ 0           : 2,097,152 fl (8 MB)
  //   Z0    @ 2,097,152   : 16,777,216 sh = 8,388,608 fl (32 MB)
  //   zT    @ 10,485,760  :  8,388,608 sh = 4,194,304 fl (16 MB)
  //   w0T   @ 14,680,064  :     49,152 sh =    24,576 fl
  //   w1T   @ 14,704,640  :     32,768 sh =    16,384 fl
  //   stats @ 14,721,024  :        768 fl          -> extent 58.9 MB
  float*          p2t  = ws;
  unsigned short* Z0   = (unsigned short*)(ws + 2097152);
  unsigned short* zT   = (unsigned short*)(ws + 10485760);
  unsigned short* w0T  = (unsigned short*)(ws + 14680064);
  unsigned short* w1T  = (unsigned short*)(ws + 14704640);
  float*          stats= ws + 14721024;

  float* sum0 = stats;        float* sq0 = stats + 256;
  float* sum1 = stats + 512;  float* sq1 = stats + 640;

  // 1: transposes + weight cvt + stats zero (all independent)
  prep<<<2129, 256, 0, stream>>>(points2, p2t, w0, w0T, w1, w1T, stats);

  // 2: 3-NN + interp + GEMM0 + BN0 stats (fully fused, sync-free)
  knn3_g0<<<RTOT / 64, 512, 0, stream>>>(xyz1, xyz2, points1, p2t,
                                         w0T, cb0, sum0, sq0, Z0);

  // 3: zT = (relu(BN0(Z0)) @ W1 + b1)^T  (BN coeffs in prologue), + sums for BN1
  gemm_mfma<1, CH1, 1><<<dim3(CH2 / 128, RTOT / 128), 256, 0, stream>>>(
      Z0, w1T, cb1, sum0, sq0, s0, bb0, sum1, sq1, zT, CH2);

  // 4: out = relu(BN1(zT)) as fp32, pure elementwise
  out_cvt<<<RTOT * CH2 / 8 / 256, 256, 0, stream>>>(
      zT, sum1, sq1, s1, bb1, (float*)d_out);
}